// Round 2
// baseline (1194.072 us; speedup 1.0000x reference)
//
#include <hip/hip_runtime.h>
#include <stdint.h>
#include <stddef.h>

// Problem constants
#define T_ 512
#define B_ 256
#define IN_ 292
#define H_ 128
#define G4_ 512   // 4*H
#define TB_ 131072  // T_*B_

typedef short bf16x8 __attribute__((ext_vector_type(8)));
typedef float f32x4 __attribute__((ext_vector_type(4)));

__device__ __forceinline__ unsigned short f2bf(float f) {
  unsigned u = __float_as_uint(f);
  u += 0x7FFFu + ((u >> 16) & 1u);   // RTNE
  return (unsigned short)(u >> 16);
}
__device__ __forceinline__ float bf2f(unsigned short s) {
  return __uint_as_float(((unsigned)s) << 16);
}
__device__ __forceinline__ bf16x8 pack8(float4 a, float4 b) {
  bf16x8 r;
  r[0]=(short)f2bf(a.x); r[1]=(short)f2bf(a.y); r[2]=(short)f2bf(a.z); r[3]=(short)f2bf(a.w);
  r[4]=(short)f2bf(b.x); r[5]=(short)f2bf(b.y); r[6]=(short)f2bf(b.z); r[7]=(short)f2bf(b.w);
  return r;
}
__device__ __forceinline__ float sigf(float x) {
  return __builtin_amdgcn_rcpf(1.0f + __expf(-x));
}
__device__ __forceinline__ float tanhf_(float x) {
  // 1 - 2/(exp(2x)+1); saturates correctly at +-inf
  return 1.0f - 2.0f * __builtin_amdgcn_rcpf(__expf(2.0f * x) + 1.0f);
}

// LDS-only barrier: waits lgkmcnt(0) (ds ops complete -> visible CU-wide),
// does NOT drain vmcnt — global prefetch loads / stores stay in flight.
// This avoids the s_waitcnt vmcnt(0) that __syncthreads() emits (workgroup
// release-fence semantics), which was putting ~900cyc HBM latency on the
// critical path of every LSTM step.
__device__ __forceinline__ void barrier_lds() {
  asm volatile("s_waitcnt lgkmcnt(0)\n\ts_barrier" ::: "memory");
}

// ---------------------------------------------------------------------------
// K1: pre[T*B][512] (bf16) = x @ W_ih^T + (b_ih + b_hh)
// Computed as D = W_ih * x^T so C-frag rows = gate index j (4 consecutive j
// per lane) and cols = row m -> 8B contiguous bf16 stores in [m][j] layout.
// Tiles: 128 m x 128 j per block, K padded 292->320 (10 x BK=32).
// ---------------------------------------------------------------------------
__global__ __launch_bounds__(256) void k1_pregemm(
    const float* __restrict__ x, const float* __restrict__ Wih,
    const float* __restrict__ bih, const float* __restrict__ bhh,
    unsigned short* __restrict__ pre) {
  __shared__ unsigned short xs[128 * 32];   // x tile  [m][k] bf16
  __shared__ unsigned short wsh[128 * 32];  // W tile  [j][k] bf16
  __shared__ float bias_s[128];

  const int m0 = blockIdx.x * 128;
  const int j0 = blockIdx.y * 128;
  const int tid = threadIdx.x;
  const int w = tid >> 6;
  const int lane = tid & 63;
  const int l15 = lane & 15;
  const int q = lane >> 4;
  const int jb = (w >> 1) * 64;  // wave's j sub-base
  const int mb = (w & 1) * 64;   // wave's m sub-base

  if (tid < 128) bias_s[tid] = bih[j0 + tid] + bhh[j0 + tid];

  f32x4 acc[4][4];  // [jsub][msub]
#pragma unroll
  for (int a = 0; a < 4; a++)
#pragma unroll
    for (int b = 0; b < 4; b++) acc[a][b] = (f32x4){0.f, 0.f, 0.f, 0.f};

  for (int kk = 0; kk < 320; kk += 32) {
    __syncthreads();  // prior-iter LDS reads done before restage
    if (kk < 288) {
      const int row = tid >> 1, half = tid & 1;
      const float* px = x + (size_t)(m0 + row) * IN_ + kk + half * 16;
      const float* pw = Wih + (size_t)(j0 + row) * IN_ + kk + half * 16;
      float4 a0 = *(const float4*)(px);      float4 a1 = *(const float4*)(px + 4);
      float4 a2 = *(const float4*)(px + 8);  float4 a3 = *(const float4*)(px + 12);
      float4 b0 = *(const float4*)(pw);      float4 b1 = *(const float4*)(pw + 4);
      float4 b2 = *(const float4*)(pw + 8);  float4 b3 = *(const float4*)(pw + 12);
      *(bf16x8*)&xs[row * 32 + half * 16]      = pack8(a0, a1);
      *(bf16x8*)&xs[row * 32 + half * 16 + 8]  = pack8(a2, a3);
      *(bf16x8*)&wsh[row * 32 + half * 16]     = pack8(b0, b1);
      *(bf16x8*)&wsh[row * 32 + half * 16 + 8] = pack8(b2, b3);
    } else {
      // k = 288..291 valid (exactly 4 floats to row end), rest zero
      if (tid < 128) {
        const int row = tid;
        float4 xa = *(const float4*)(x + (size_t)(m0 + row) * IN_ + 288);
        float4 wa = *(const float4*)(Wih + (size_t)(j0 + row) * IN_ + 288);
        float4 z4 = {0.f, 0.f, 0.f, 0.f};
        bf16x8 z8 = pack8(z4, z4);
        *(bf16x8*)&xs[row * 32]      = pack8(xa, z4);
        *(bf16x8*)&xs[row * 32 + 8]  = z8;
        *(bf16x8*)&xs[row * 32 + 16] = z8;
        *(bf16x8*)&xs[row * 32 + 24] = z8;
        *(bf16x8*)&wsh[row * 32]      = pack8(wa, z4);
        *(bf16x8*)&wsh[row * 32 + 8]  = z8;
        *(bf16x8*)&wsh[row * 32 + 16] = z8;
        *(bf16x8*)&wsh[row * 32 + 24] = z8;
      }
    }
    __syncthreads();
    bf16x8 af[4], bfr[4];
#pragma unroll
    for (int s = 0; s < 4; s++)
      af[s] = *(bf16x8*)&wsh[(jb + 16 * s + l15) * 32 + q * 8];
#pragma unroll
    for (int s = 0; s < 4; s++)
      bfr[s] = *(bf16x8*)&xs[(mb + 16 * s + l15) * 32 + q * 8];
#pragma unroll
    for (int js = 0; js < 4; js++)
#pragma unroll
      for (int ms = 0; ms < 4; ms++)
        acc[js][ms] = __builtin_amdgcn_mfma_f32_16x16x32_bf16(
            af[js], bfr[ms], acc[js][ms], 0, 0, 0);
  }

#pragma unroll
  for (int js = 0; js < 4; js++) {
    float4 bv = *(float4*)&bias_s[jb + 16 * js + 4 * q];
#pragma unroll
    for (int ms = 0; ms < 4; ms++) {
      const int m = m0 + mb + 16 * ms + l15;
      const int j = j0 + jb + 16 * js + 4 * q;
      ushort4 st;
      st.x = f2bf(acc[js][ms][0] + bv.x);
      st.y = f2bf(acc[js][ms][1] + bv.y);
      st.z = f2bf(acc[js][ms][2] + bv.z);
      st.w = f2bf(acc[js][ms][3] + bv.w);
      *(ushort4*)&pre[(size_t)m * G4_ + j] = st;
    }
  }
}

// ---------------------------------------------------------------------------
// K2: sequential LSTM over T. 16 blocks (one per 16-batch group), 512 thr.
// Wave w owns gate-tiles {w, w+8, w+16, w+24} => lane holds i,f,g,o for the
// same (b = lane&15, k = 16w + 4q + r) in-lane. W_hh resident in registers
// as bf16 A-frags. h double-buffered in LDS (bf16, row pad 136). c in VGPRs.
// One LDS-only barrier per step; pre prefetched 2 steps ahead so the HBM
// load latency never hits the critical path.
// ---------------------------------------------------------------------------
__global__ __launch_bounds__(512) void k2_lstm(
    const unsigned short* __restrict__ pre, const float* __restrict__ Whh,
    const float* __restrict__ h0, const float* __restrict__ c0,
    const int* __restrict__ done, unsigned short* __restrict__ hidden) {
  __shared__ unsigned short hs[2][16 * 136];
  __shared__ int dns[T_ * 16];  // done slice [t][b16], 32 KB

  const int bg = blockIdx.x;
  const int tid = threadIdx.x;
  const int w = tid >> 6;
  const int lane = tid & 63;
  const int l15 = lane & 15;
  const int q = lane >> 4;
  const int bglob = bg * 16 + l15;
  const int kcell = 16 * w + 4 * q;

  // stage done column slice: thread t -> 16 ints
  {
    const int* p = done + (size_t)tid * B_ + bg * 16;
    int4 d0 = *(const int4*)(p);     int4 d1 = *(const int4*)(p + 4);
    int4 d2 = *(const int4*)(p + 8); int4 d3 = *(const int4*)(p + 12);
    *(int4*)&dns[tid * 16]      = d0;
    *(int4*)&dns[tid * 16 + 4]  = d1;
    *(int4*)&dns[tid * 16 + 8]  = d2;
    *(int4*)&dns[tid * 16 + 12] = d3;
  }

  // resident W_hh A-frags: A[m=lane&15][k=q*8+j']
  bf16x8 wf[4][4];
#pragma unroll
  for (int tI = 0; tI < 4; tI++) {
    const int jg = 16 * (w + 8 * tI) + l15;
#pragma unroll
    for (int kc = 0; kc < 4; kc++) {
      const float* p = Whh + (size_t)jg * H_ + kc * 32 + q * 8;
      float4 u0 = *(const float4*)p;
      float4 u1 = *(const float4*)(p + 4);
      wf[tI][kc] = pack8(u0, u1);
    }
  }

  // c init (fp32 regs), h init -> LDS buf0 bf16
  float c_[4];
  {
    float4 cv = *(const float4*)(c0 + (size_t)bglob * H_ + kcell);
    c_[0] = cv.x; c_[1] = cv.y; c_[2] = cv.z; c_[3] = cv.w;
    const int b = tid >> 5, k = (tid & 31) * 4;
    float4 hv = *(const float4*)(h0 + (size_t)(bg * 16 + b) * H_ + k);
    ushort4 hp = {f2bf(hv.x), f2bf(hv.y), f2bf(hv.z), f2bf(hv.w)};
    *(ushort4*)&hs[0][b * 136 + k] = hp;
  }
  __syncthreads();

  // prefetch pre for t=0 and t=1 (distance-2 pipeline)
  ushort4 pr[4], prn[4];
  {
    const unsigned short* pb0 = pre + (size_t)bglob * G4_;
    const unsigned short* pb1 = pre + ((size_t)B_ + bglob) * G4_;
#pragma unroll
    for (int tI = 0; tI < 4; tI++) {
      pr[tI]  = *(const ushort4*)&pb0[16 * (w + 8 * tI) + 4 * q];
      prn[tI] = *(const ushort4*)&pb1[16 * (w + 8 * tI) + 4 * q];
    }
  }

#pragma unroll 1
  for (int t = 0; t < T_; t++) {
    // issue prefetch for t+2 (lands 2 barriers later -> latency fully hidden)
    ushort4 pr2[4];
    const int tn = (t + 2 < T_) ? t + 2 : T_ - 1;
    const unsigned short* pb = pre + ((size_t)tn * B_ + bglob) * G4_;
#pragma unroll
    for (int tI = 0; tI < 4; tI++)
      pr2[tI] = *(const ushort4*)&pb[16 * (w + 8 * tI) + 4 * q];

    const int dn = dns[t * 16 + l15];

    // h B-frags from LDS buf[t&1], masked by done[t] (reset => h treated as 0)
    const unsigned short* hb = hs[t & 1];
    bf16x8 hf[4];
#pragma unroll
    for (int kc = 0; kc < 4; kc++) {
      bf16x8 v = *(const bf16x8*)&hb[l15 * 136 + kc * 32 + q * 8];
      if (dn) v = (bf16x8){0, 0, 0, 0, 0, 0, 0, 0};
      hf[kc] = v;
    }

    f32x4 acc[4];
#pragma unroll
    for (int tI = 0; tI < 4; tI++) acc[tI] = (f32x4){0.f, 0.f, 0.f, 0.f};
#pragma unroll
    for (int tI = 0; tI < 4; tI++)
#pragma unroll
      for (int kc = 0; kc < 4; kc++)
        acc[tI] = __builtin_amdgcn_mfma_f32_16x16x32_bf16(
            wf[tI][kc], hf[kc], acc[tI], 0, 0, 0);

    const float m = dn ? 0.0f : 1.0f;
    ushort4 hw;
    unsigned short* hq = &hw.x;
#pragma unroll
    for (int r = 0; r < 4; r++) {
      const float iv = acc[0][r] + bf2f((&pr[0].x)[r]);
      const float fv = acc[1][r] + bf2f((&pr[1].x)[r]);
      const float gv = acc[2][r] + bf2f((&pr[2].x)[r]);
      const float ov = acc[3][r] + bf2f((&pr[3].x)[r]);
      float cc = c_[r] * m;
      cc = sigf(fv) * cc + sigf(iv) * tanhf_(gv);
      c_[r] = cc;
      hq[r] = f2bf(sigf(ov) * tanhf_(cc));
    }
    // write new h into the OTHER buffer; current buffer stays intact until
    // every wave passes the end-of-step barrier.
    *(ushort4*)&hs[(t + 1) & 1][l15 * 136 + kcell] = hw;
    *(ushort4*)&hidden[((size_t)t * B_ + bglob) * H_ + kcell] = hw;
#pragma unroll
    for (int tI = 0; tI < 4; tI++) { pr[tI] = prn[tI]; prn[tI] = pr2[tI]; }
    barrier_lds();  // lgkmcnt(0)+s_barrier only; vmcnt stays in flight
  }
}

// ---------------------------------------------------------------------------
// K3: out[T*B][13] = hidden @ [W_pi; W_v]^T + [b_pi; b_v]
// Block: 64 rows, 4 waves (16 rows each). W resident in A-frags (rows 13..15
// zero). D rows = output channel n, cols = m.
// ---------------------------------------------------------------------------
__global__ __launch_bounds__(256) void k3_head(
    const unsigned short* __restrict__ hidden, const float* __restrict__ Wpi,
    const float* __restrict__ bpi, const float* __restrict__ Wv,
    const float* __restrict__ bv, float* __restrict__ out) {
  __shared__ unsigned short hs3[64 * 136];
  __shared__ float bias_s[16];

  const int tid = threadIdx.x;
  const int w = tid >> 6;
  const int lane = tid & 63;
  const int l15 = lane & 15;
  const int q = lane >> 4;
  const int m0 = blockIdx.x * 64;

  if (tid < 16) bias_s[tid] = (tid < 12) ? bpi[tid] : ((tid == 12) ? bv[0] : 0.f);

  bf16x8 wf3[4];
#pragma unroll
  for (int kc = 0; kc < 4; kc++) {
    float4 u0 = {0.f, 0.f, 0.f, 0.f}, u1 = {0.f, 0.f, 0.f, 0.f};
    if (l15 < 12) {
      const float* p = Wpi + (size_t)l15 * H_ + kc * 32 + q * 8;
      u0 = *(const float4*)p; u1 = *(const float4*)(p + 4);
    } else if (l15 == 12) {
      const float* p = Wv + kc * 32 + q * 8;
      u0 = *(const float4*)p; u1 = *(const float4*)(p + 4);
    }
    wf3[kc] = pack8(u0, u1);
  }

  // stage 64 rows of hidden (bf16 passthrough)
  {
    const int row = tid >> 2, ks = (tid & 3) * 32;
    const unsigned short* p = hidden + (size_t)(m0 + row) * H_ + ks;
#pragma unroll
    for (int i = 0; i < 4; i++)
      *(uint4*)&hs3[row * 136 + ks + i * 8] = *(const uint4*)(p + i * 8);
  }
  __syncthreads();

  f32x4 acc = (f32x4){0.f, 0.f, 0.f, 0.f};
#pragma unroll
  for (int kc = 0; kc < 4; kc++) {
    bf16x8 hf = *(bf16x8*)&hs3[(16 * w + l15) * 136 + kc * 32 + q * 8];
    acc = __builtin_amdgcn_mfma_f32_16x16x32_bf16(wf3[kc], hf, acc, 0, 0, 0);
  }

  const float4 bb = *(float4*)&bias_s[4 * q];
  const int m = m0 + 16 * w + l15;
  const size_t ro = (size_t)m * 13;
  float v0 = acc[0] + bb.x, v1 = acc[1] + bb.y, v2 = acc[2] + bb.z, v3 = acc[3] + bb.w;
  if (q < 3) {
    out[ro + 4 * q + 0] = v0;
    out[ro + 4 * q + 1] = v1;
    out[ro + 4 * q + 2] = v2;
    out[ro + 4 * q + 3] = v3;
  } else {
    out[ro + 12] = v0;  // n == 12 (value); n = 13..15 dropped
  }
}

// ---------------------------------------------------------------------------
// Workspace layout (requires >= 160 MB):
//   pre    bf16 [131072][512]  : 134,217,728 B  @ offset 0
//   hidden bf16 [131072][128]  :  33,554,432 B  @ offset 134,217,728
// ---------------------------------------------------------------------------
extern "C" void kernel_launch(void* const* d_in, const int* in_sizes, int n_in,
                              void* d_out, int out_size, void* d_ws, size_t ws_size,
                              hipStream_t stream) {
  const float* x    = (const float*)d_in[0];
  const int* done   = (const int*)d_in[1];
  const float* h0   = (const float*)d_in[2];
  const float* c0   = (const float*)d_in[3];
  const float* Wih  = (const float*)d_in[4];
  const float* Whh  = (const float*)d_in[5];
  const float* bih  = (const float*)d_in[6];
  const float* bhh  = (const float*)d_in[7];
  const float* Wpi  = (const float*)d_in[8];
  const float* bpi  = (const float*)d_in[9];
  const float* Wv   = (const float*)d_in[10];
  const float* bv   = (const float*)d_in[11];
  (void)in_sizes; (void)n_in; (void)out_size; (void)ws_size;

  unsigned short* pre = (unsigned short*)d_ws;
  unsigned short* hidden = pre + (size_t)TB_ * G4_;
  float* out = (float*)d_out;

  k1_pregemm<<<dim3(TB_ / 128, G4_ / 128), 256, 0, stream>>>(x, Wih, bih, bhh, pre);
  k2_lstm<<<16, 512, 0, stream>>>(pre, Whh, h0, c0, done, hidden);
  k3_head<<<TB_ / 64, 256, 0, stream>>>(hidden, Wpi, bpi, Wv, bv, out);
}

// Round 3
// 582.118 us; speedup vs baseline: 2.0513x; 2.0513x over previous
//
#include <hip/hip_runtime.h>
#include <stdint.h>
#include <stddef.h>

// Problem constants
#define T_ 512
#define B_ 256
#define IN_ 292
#define H_ 128
#define G4_ 512     // 4*H
#define TB_ 131072  // T_*B_
#define LCH 32      // time-chunk length for the segment scan
#define NCH 16      // number of chunks (T_/LCH)

typedef short bf16x8 __attribute__((ext_vector_type(8)));
typedef float f32x4 __attribute__((ext_vector_type(4)));

__device__ __forceinline__ unsigned short f2bf(float f) {
  unsigned u = __float_as_uint(f);
  u += 0x7FFFu + ((u >> 16) & 1u);   // RTNE
  return (unsigned short)(u >> 16);
}
__device__ __forceinline__ float bf2f(unsigned short s) {
  return __uint_as_float(((unsigned)s) << 16);
}
__device__ __forceinline__ bf16x8 pack8(float4 a, float4 b) {
  bf16x8 r;
  r[0]=(short)f2bf(a.x); r[1]=(short)f2bf(a.y); r[2]=(short)f2bf(a.z); r[3]=(short)f2bf(a.w);
  r[4]=(short)f2bf(b.x); r[5]=(short)f2bf(b.y); r[6]=(short)f2bf(b.z); r[7]=(short)f2bf(b.w);
  return r;
}
__device__ __forceinline__ float sigf(float x) {
  return __builtin_amdgcn_rcpf(1.0f + __expf(-x));
}
__device__ __forceinline__ float tanhf_(float x) {
  // 1 - 2/(exp(2x)+1); saturates correctly at +-inf (exp->Inf => rcp->0 => 1)
  return 1.0f - 2.0f * __builtin_amdgcn_rcpf(__expf(2.0f * x) + 1.0f);
}

// LDS-only barrier: lgkmcnt(0)+s_barrier, leaves global loads/stores in flight.
__device__ __forceinline__ void barrier_lds() {
  asm volatile("s_waitcnt lgkmcnt(0)\n\ts_barrier" ::: "memory");
}

// ---------------------------------------------------------------------------
// K1: pre[T*B][512] (bf16) = x @ W_ih^T + (b_ih + b_hh)   (unchanged)
// ---------------------------------------------------------------------------
__global__ __launch_bounds__(256) void k1_pregemm(
    const float* __restrict__ x, const float* __restrict__ Wih,
    const float* __restrict__ bih, const float* __restrict__ bhh,
    unsigned short* __restrict__ pre) {
  __shared__ unsigned short xs[128 * 32];   // x tile  [m][k] bf16
  __shared__ unsigned short wsh[128 * 32];  // W tile  [j][k] bf16
  __shared__ float bias_s[128];

  const int m0 = blockIdx.x * 128;
  const int j0 = blockIdx.y * 128;
  const int tid = threadIdx.x;
  const int w = tid >> 6;
  const int lane = tid & 63;
  const int l15 = lane & 15;
  const int q = lane >> 4;
  const int jb = (w >> 1) * 64;
  const int mb = (w & 1) * 64;

  if (tid < 128) bias_s[tid] = bih[j0 + tid] + bhh[j0 + tid];

  f32x4 acc[4][4];
#pragma unroll
  for (int a = 0; a < 4; a++)
#pragma unroll
    for (int b = 0; b < 4; b++) acc[a][b] = (f32x4){0.f, 0.f, 0.f, 0.f};

  for (int kk = 0; kk < 320; kk += 32) {
    __syncthreads();
    if (kk < 288) {
      const int row = tid >> 1, half = tid & 1;
      const float* px = x + (size_t)(m0 + row) * IN_ + kk + half * 16;
      const float* pw = Wih + (size_t)(j0 + row) * IN_ + kk + half * 16;
      float4 a0 = *(const float4*)(px);      float4 a1 = *(const float4*)(px + 4);
      float4 a2 = *(const float4*)(px + 8);  float4 a3 = *(const float4*)(px + 12);
      float4 b0 = *(const float4*)(pw);      float4 b1 = *(const float4*)(pw + 4);
      float4 b2 = *(const float4*)(pw + 8);  float4 b3 = *(const float4*)(pw + 12);
      *(bf16x8*)&xs[row * 32 + half * 16]      = pack8(a0, a1);
      *(bf16x8*)&xs[row * 32 + half * 16 + 8]  = pack8(a2, a3);
      *(bf16x8*)&wsh[row * 32 + half * 16]     = pack8(b0, b1);
      *(bf16x8*)&wsh[row * 32 + half * 16 + 8] = pack8(b2, b3);
    } else {
      if (tid < 128) {
        const int row = tid;
        float4 xa = *(const float4*)(x + (size_t)(m0 + row) * IN_ + 288);
        float4 wa = *(const float4*)(Wih + (size_t)(j0 + row) * IN_ + 288);
        float4 z4 = {0.f, 0.f, 0.f, 0.f};
        bf16x8 z8 = pack8(z4, z4);
        *(bf16x8*)&xs[row * 32]      = pack8(xa, z4);
        *(bf16x8*)&xs[row * 32 + 8]  = z8;
        *(bf16x8*)&xs[row * 32 + 16] = z8;
        *(bf16x8*)&xs[row * 32 + 24] = z8;
        *(bf16x8*)&wsh[row * 32]      = pack8(wa, z4);
        *(bf16x8*)&wsh[row * 32 + 8]  = z8;
        *(bf16x8*)&wsh[row * 32 + 16] = z8;
        *(bf16x8*)&wsh[row * 32 + 24] = z8;
      }
    }
    __syncthreads();
    bf16x8 af[4], bfr[4];
#pragma unroll
    for (int s = 0; s < 4; s++)
      af[s] = *(bf16x8*)&wsh[(jb + 16 * s + l15) * 32 + q * 8];
#pragma unroll
    for (int s = 0; s < 4; s++)
      bfr[s] = *(bf16x8*)&xs[(mb + 16 * s + l15) * 32 + q * 8];
#pragma unroll
    for (int js = 0; js < 4; js++)
#pragma unroll
      for (int ms = 0; ms < 4; ms++)
        acc[js][ms] = __builtin_amdgcn_mfma_f32_16x16x32_bf16(
            af[js], bfr[ms], acc[js][ms], 0, 0, 0);
  }

#pragma unroll
  for (int js = 0; js < 4; js++) {
    float4 bv = *(float4*)&bias_s[jb + 16 * js + 4 * q];
#pragma unroll
    for (int ms = 0; ms < 4; ms++) {
      const int m = m0 + mb + 16 * ms + l15;
      const int j = j0 + jb + 16 * js + 4 * q;
      ushort4 st;
      st.x = f2bf(acc[js][ms][0] + bv.x);
      st.y = f2bf(acc[js][ms][1] + bv.y);
      st.z = f2bf(acc[js][ms][2] + bv.z);
      st.w = f2bf(acc[js][ms][3] + bv.w);
      *(ushort4*)&pre[(size_t)m * G4_ + j] = st;
    }
  }
}

// ---------------------------------------------------------------------------
// Segment-scan LSTM. done=1 at step t zeroes (h,c) BEFORE the cell, so every
// reset starts an independent segment. P(done)=0.5 => segments are short.
//
// K2a: 256 blocks = (bg 0..15) x (chunk 0..15), chunk = 32 steps. Each block
// runs its chunk from (h,c)=0; per-batch outputs are exact (and stored) from
// the first in-chunk reset onward. Chunk-final h (bf16) and c (fp32) are
// stashed so K2b can pick up carries. Garbage pre-reset state is bounded
// (h in (-1,1), c grows <= +1/step) => no NaN/Inf.
//
// K2b: 16 blocks (bg). Sequentially walks chunks with the TRUE carry,
// recomputing only each chunk's prefix (steps before that batch's first
// reset, expected max ~5) and storing those. At chunk end, batches that hit
// a reset take K2a's final state as carry. Exact for any done pattern
// (a reset-free chunk just runs all 32 steps in K2b).
// ---------------------------------------------------------------------------
__global__ __launch_bounds__(512) void k2a_chunk(
    const unsigned short* __restrict__ pre, const float* __restrict__ Whh,
    const int* __restrict__ done, unsigned short* __restrict__ hidden,
    unsigned short* __restrict__ hfin, float* __restrict__ cfin) {
  __shared__ unsigned short hs[2][16 * 136];
  __shared__ int dns[LCH * 16];

  const int bg = blockIdx.x & 15;
  const int ck = blockIdx.x >> 4;
  const int t0 = ck * LCH;
  const int tid = threadIdx.x;
  const int w = tid >> 6;
  const int lane = tid & 63;
  const int l15 = lane & 15;
  const int q = lane >> 4;
  const int bglob = bg * 16 + l15;
  const int kcell = 16 * w + 4 * q;

  // stage done slice [LCH][16]
  {
    const int row = tid >> 4, col = tid & 15;
    dns[tid] = done[(size_t)(t0 + row) * B_ + bg * 16 + col];
  }

  // resident W_hh A-frags
  bf16x8 wf[4][4];
#pragma unroll
  for (int tI = 0; tI < 4; tI++) {
    const int jg = 16 * (w + 8 * tI) + l15;
#pragma unroll
    for (int kc = 0; kc < 4; kc++) {
      const float* p = Whh + (size_t)jg * H_ + kc * 32 + q * 8;
      float4 u0 = *(const float4*)p;
      float4 u1 = *(const float4*)(p + 4);
      wf[tI][kc] = pack8(u0, u1);
    }
  }

  // zero-init state (unknown carry-in; validity starts false)
  float c_[4] = {0.f, 0.f, 0.f, 0.f};
  {
    const int b = tid >> 5, k = (tid & 31) * 4;
    *(ushort4*)&hs[0][b * 136 + k] = (ushort4){0, 0, 0, 0};
  }
  bool vld = false;
  __syncthreads();

  // distance-2 pre prefetch
  ushort4 pr[4], prn[4];
  {
    const unsigned short* pb0 = pre + ((size_t)t0 * B_ + bglob) * G4_;
    const unsigned short* pb1 = pre + ((size_t)(t0 + 1) * B_ + bglob) * G4_;
#pragma unroll
    for (int tI = 0; tI < 4; tI++) {
      pr[tI]  = *(const ushort4*)&pb0[16 * (w + 8 * tI) + 4 * q];
      prn[tI] = *(const ushort4*)&pb1[16 * (w + 8 * tI) + 4 * q];
    }
  }

  ushort4 hw = {0, 0, 0, 0};
#pragma unroll 1
  for (int u = 0; u < LCH; u++) {
    const int t = t0 + u;
    ushort4 pr2[4];
    const int un = (u + 2 < LCH) ? u + 2 : LCH - 1;
    const unsigned short* pb = pre + ((size_t)(t0 + un) * B_ + bglob) * G4_;
#pragma unroll
    for (int tI = 0; tI < 4; tI++)
      pr2[tI] = *(const ushort4*)&pb[16 * (w + 8 * tI) + 4 * q];

    const int dn = dns[u * 16 + l15];
    vld = vld || (dn != 0);

    const unsigned short* hb = hs[u & 1];
    bf16x8 hf[4];
#pragma unroll
    for (int kc = 0; kc < 4; kc++) {
      bf16x8 v = *(const bf16x8*)&hb[l15 * 136 + kc * 32 + q * 8];
      if (dn) v = (bf16x8){0, 0, 0, 0, 0, 0, 0, 0};
      hf[kc] = v;
    }

    f32x4 acc[4];
#pragma unroll
    for (int tI = 0; tI < 4; tI++) acc[tI] = (f32x4){0.f, 0.f, 0.f, 0.f};
#pragma unroll
    for (int tI = 0; tI < 4; tI++)
#pragma unroll
      for (int kc = 0; kc < 4; kc++)
        acc[tI] = __builtin_amdgcn_mfma_f32_16x16x32_bf16(
            wf[tI][kc], hf[kc], acc[tI], 0, 0, 0);

    const float m = dn ? 0.0f : 1.0f;
    unsigned short* hq = &hw.x;
#pragma unroll
    for (int r = 0; r < 4; r++) {
      const float iv = acc[0][r] + bf2f((&pr[0].x)[r]);
      const float fv = acc[1][r] + bf2f((&pr[1].x)[r]);
      const float gv = acc[2][r] + bf2f((&pr[2].x)[r]);
      const float ov = acc[3][r] + bf2f((&pr[3].x)[r]);
      float cc = c_[r] * m;
      cc = sigf(fv) * cc + sigf(iv) * tanhf_(gv);
      c_[r] = cc;
      hq[r] = f2bf(sigf(ov) * tanhf_(cc));
    }
    *(ushort4*)&hs[(u + 1) & 1][l15 * 136 + kcell] = hw;
    if (vld)
      *(ushort4*)&hidden[((size_t)t * B_ + bglob) * H_ + kcell] = hw;
#pragma unroll
    for (int tI = 0; tI < 4; tI++) { pr[tI] = prn[tI]; prn[tI] = pr2[tI]; }
    barrier_lds();
  }

  // chunk-final state for K2b's carry pickup
  *(ushort4*)&hfin[((size_t)ck * B_ + bglob) * H_ + kcell] = hw;
  float4 cv = {c_[0], c_[1], c_[2], c_[3]};
  *(float4*)&cfin[((size_t)ck * B_ + bglob) * H_ + kcell] = cv;
}

__global__ __launch_bounds__(512) void k2b_fix(
    const unsigned short* __restrict__ pre, const float* __restrict__ Whh,
    const float* __restrict__ h0, const float* __restrict__ c0,
    const int* __restrict__ done, unsigned short* __restrict__ hidden,
    const unsigned short* __restrict__ hfin, const float* __restrict__ cfin) {
  __shared__ unsigned short hs[2][16 * 136];
  __shared__ int dns[T_ * 16];  // 32 KB

  const int bg = blockIdx.x;
  const int tid = threadIdx.x;
  const int w = tid >> 6;
  const int lane = tid & 63;
  const int l15 = lane & 15;
  const int q = lane >> 4;
  const int bglob = bg * 16 + l15;
  const int kcell = 16 * w + 4 * q;

  {
    const int* p = done + (size_t)tid * B_ + bg * 16;
    int4 d0 = *(const int4*)(p);     int4 d1 = *(const int4*)(p + 4);
    int4 d2 = *(const int4*)(p + 8); int4 d3 = *(const int4*)(p + 12);
    *(int4*)&dns[tid * 16]      = d0;
    *(int4*)&dns[tid * 16 + 4]  = d1;
    *(int4*)&dns[tid * 16 + 8]  = d2;
    *(int4*)&dns[tid * 16 + 12] = d3;
  }

  bf16x8 wf[4][4];
#pragma unroll
  for (int tI = 0; tI < 4; tI++) {
    const int jg = 16 * (w + 8 * tI) + l15;
#pragma unroll
    for (int kc = 0; kc < 4; kc++) {
      const float* p = Whh + (size_t)jg * H_ + kc * 32 + q * 8;
      float4 u0 = *(const float4*)p;
      float4 u1 = *(const float4*)(p + 4);
      wf[tI][kc] = pack8(u0, u1);
    }
  }

  // true carry-in at t=0
  float c_[4];
  {
    float4 cv = *(const float4*)(c0 + (size_t)bglob * H_ + kcell);
    c_[0] = cv.x; c_[1] = cv.y; c_[2] = cv.z; c_[3] = cv.w;
    const int b = tid >> 5, k = (tid & 31) * 4;
    float4 hv = *(const float4*)(h0 + (size_t)(bg * 16 + b) * H_ + k);
    ushort4 hp = {f2bf(hv.x), f2bf(hv.y), f2bf(hv.z), f2bf(hv.w)};
    *(ushort4*)&hs[0][b * 136 + k] = hp;
  }
  int cur = 0;
  __syncthreads();

#pragma unroll 1
  for (int ck = 0; ck < NCH; ck++) {
    const int t0 = ck * LCH;
    bool act = true;  // b needs prefix recompute until its first in-chunk reset

    ushort4 pr[4];
    {
      const unsigned short* pb = pre + ((size_t)t0 * B_ + bglob) * G4_;
#pragma unroll
      for (int tI = 0; tI < 4; tI++)
        pr[tI] = *(const ushort4*)&pb[16 * (w + 8 * tI) + 4 * q];
    }

#pragma unroll 1
    for (int u = 0; u < LCH; u++) {
      const int t = t0 + u;
      const int dn = dns[t * 16 + l15];
      const bool nact = act && (dn == 0);
      // block-uniform (act depends only on l15): all waves agree
      if (__ballot(nact) == 0ULL) { act = false; break; }
      act = nact;

      ushort4 prn[4];
      const int un = (u + 1 < LCH) ? u + 1 : LCH - 1;
      const unsigned short* pb = pre + ((size_t)(t0 + un) * B_ + bglob) * G4_;
#pragma unroll
      for (int tI = 0; tI < 4; tI++)
        prn[tI] = *(const ushort4*)&pb[16 * (w + 8 * tI) + 4 * q];

      const unsigned short* hb = hs[cur];
      bf16x8 hf[4];
#pragma unroll
      for (int kc = 0; kc < 4; kc++)
        hf[kc] = *(const bf16x8*)&hb[l15 * 136 + kc * 32 + q * 8];

      f32x4 acc[4];
#pragma unroll
      for (int tI = 0; tI < 4; tI++) acc[tI] = (f32x4){0.f, 0.f, 0.f, 0.f};
#pragma unroll
      for (int tI = 0; tI < 4; tI++)
#pragma unroll
        for (int kc = 0; kc < 4; kc++)
          acc[tI] = __builtin_amdgcn_mfma_f32_16x16x32_bf16(
              wf[tI][kc], hf[kc], acc[tI], 0, 0, 0);

      ushort4 hw;
      unsigned short* hq = &hw.x;
#pragma unroll
      for (int r = 0; r < 4; r++) {
        const float iv = acc[0][r] + bf2f((&pr[0].x)[r]);
        const float fv = acc[1][r] + bf2f((&pr[1].x)[r]);
        const float gv = acc[2][r] + bf2f((&pr[2].x)[r]);
        const float ov = acc[3][r] + bf2f((&pr[3].x)[r]);
        float cc = sigf(fv) * c_[r] + sigf(iv) * tanhf_(gv);
        c_[r] = cc;
        hq[r] = f2bf(sigf(ov) * tanhf_(cc));
      }
      *(ushort4*)&hs[cur ^ 1][l15 * 136 + kcell] = hw;
      if (act)
        *(ushort4*)&hidden[((size_t)t * B_ + bglob) * H_ + kcell] = hw;
#pragma unroll
      for (int tI = 0; tI < 4; tI++) pr[tI] = prn[tI];
      barrier_lds();
      cur ^= 1;
    }

    // chunk boundary: batches that hit a reset adopt K2a's exact final state
    if (!act) {
      ushort4 hv = *(const ushort4*)&hfin[((size_t)ck * B_ + bglob) * H_ + kcell];
      float4 cv = *(const float4*)&cfin[((size_t)ck * B_ + bglob) * H_ + kcell];
      c_[0] = cv.x; c_[1] = cv.y; c_[2] = cv.z; c_[3] = cv.w;
      *(ushort4*)&hs[cur][l15 * 136 + kcell] = hv;
    }
    barrier_lds();
  }
}

// ---------------------------------------------------------------------------
// K3: out[T*B][13] = hidden @ [W_pi; W_v]^T + [b_pi; b_v]   (unchanged)
// ---------------------------------------------------------------------------
__global__ __launch_bounds__(256) void k3_head(
    const unsigned short* __restrict__ hidden, const float* __restrict__ Wpi,
    const float* __restrict__ bpi, const float* __restrict__ Wv,
    const float* __restrict__ bv, float* __restrict__ out) {
  __shared__ unsigned short hs3[64 * 136];
  __shared__ float bias_s[16];

  const int tid = threadIdx.x;
  const int w = tid >> 6;
  const int lane = tid & 63;
  const int l15 = lane & 15;
  const int q = lane >> 4;
  const int m0 = blockIdx.x * 64;

  if (tid < 16) bias_s[tid] = (tid < 12) ? bpi[tid] : ((tid == 12) ? bv[0] : 0.f);

  bf16x8 wf3[4];
#pragma unroll
  for (int kc = 0; kc < 4; kc++) {
    float4 u0 = {0.f, 0.f, 0.f, 0.f}, u1 = {0.f, 0.f, 0.f, 0.f};
    if (l15 < 12) {
      const float* p = Wpi + (size_t)l15 * H_ + kc * 32 + q * 8;
      u0 = *(const float4*)p; u1 = *(const float4*)(p + 4);
    } else if (l15 == 12) {
      const float* p = Wv + kc * 32 + q * 8;
      u0 = *(const float4*)p; u1 = *(const float4*)(p + 4);
    }
    wf3[kc] = pack8(u0, u1);
  }

  {
    const int row = tid >> 2, ks = (tid & 3) * 32;
    const unsigned short* p = hidden + (size_t)(m0 + row) * H_ + ks;
#pragma unroll
    for (int i = 0; i < 4; i++)
      *(uint4*)&hs3[row * 136 + ks + i * 8] = *(const uint4*)(p + i * 8);
  }
  __syncthreads();

  f32x4 acc = (f32x4){0.f, 0.f, 0.f, 0.f};
#pragma unroll
  for (int kc = 0; kc < 4; kc++) {
    bf16x8 hf = *(bf16x8*)&hs3[(16 * w + l15) * 136 + kc * 32 + q * 8];
    acc = __builtin_amdgcn_mfma_f32_16x16x32_bf16(wf3[kc], hf, acc, 0, 0, 0);
  }

  const float4 bb = *(float4*)&bias_s[4 * q];
  const int m = m0 + 16 * w + l15;
  const size_t ro = (size_t)m * 13;
  float v0 = acc[0] + bb.x, v1 = acc[1] + bb.y, v2 = acc[2] + bb.z, v3 = acc[3] + bb.w;
  if (q < 3) {
    out[ro + 4 * q + 0] = v0;
    out[ro + 4 * q + 1] = v1;
    out[ro + 4 * q + 2] = v2;
    out[ro + 4 * q + 3] = v3;
  } else {
    out[ro + 12] = v0;
  }
}

// ---------------------------------------------------------------------------
// Workspace layout (ws, same footprint as round 1 — 160 MB):
//   pre    bf16 [131072][512]  : 134,217,728 B @ 0
//   hidden bf16 [131072][128]  :  33,554,432 B @ 134,217,728
// K2a->K2b chunk-final scratch lives in d_out (6.8 MB, dead until K3
// overwrites every element):
//   hfin bf16 [16][256][128] : 1,048,576 B @ d_out+0
//   cfin fp32 [16][256][128] : 2,097,152 B @ d_out+1,048,576
// ---------------------------------------------------------------------------
extern "C" void kernel_launch(void* const* d_in, const int* in_sizes, int n_in,
                              void* d_out, int out_size, void* d_ws, size_t ws_size,
                              hipStream_t stream) {
  const float* x    = (const float*)d_in[0];
  const int* done   = (const int*)d_in[1];
  const float* h0   = (const float*)d_in[2];
  const float* c0   = (const float*)d_in[3];
  const float* Wih  = (const float*)d_in[4];
  const float* Whh  = (const float*)d_in[5];
  const float* bih  = (const float*)d_in[6];
  const float* bhh  = (const float*)d_in[7];
  const float* Wpi  = (const float*)d_in[8];
  const float* bpi  = (const float*)d_in[9];
  const float* Wv   = (const float*)d_in[10];
  const float* bv   = (const float*)d_in[11];
  (void)in_sizes; (void)n_in; (void)out_size; (void)ws_size;

  unsigned short* pre = (unsigned short*)d_ws;
  unsigned short* hidden = pre + (size_t)TB_ * G4_;
  unsigned short* hfin = (unsigned short*)d_out;
  float* cfin = (float*)((char*)d_out + (size_t)NCH * B_ * H_ * 2);
  float* out = (float*)d_out;

  k1_pregemm<<<dim3(TB_ / 128, G4_ / 128), 256, 0, stream>>>(x, Wih, bih, bhh, pre);
  k2a_chunk<<<256, 512, 0, stream>>>(pre, Whh, done, hidden, hfin, cfin);
  k2b_fix<<<16, 512, 0, stream>>>(pre, Whh, h0, c0, done, hidden, hfin, cfin);
  k3_head<<<TB_ / 64, 256, 0, stream>>>(hidden, Wpi, bpi, Wv, bv, out);
}

// Round 4
// 506.597 us; speedup vs baseline: 2.3570x; 1.1491x over previous
//
#include <hip/hip_runtime.h>
#include <stdint.h>
#include <stddef.h>

// Problem constants
#define T_ 512
#define B_ 256
#define IN_ 292
#define H_ 128
#define G4_ 512     // 4*H
#define TB_ 131072  // T_*B_
#define LCH 32      // time-chunk length for the segment scan
#define NCH 16      // number of chunks (T_/LCH)
#define KP_ 320     // K padded to 10*32

typedef short bf16x8 __attribute__((ext_vector_type(8)));
typedef float f32x4 __attribute__((ext_vector_type(4)));
typedef unsigned int u32t;

__device__ __forceinline__ unsigned short f2bf(float f) {
  unsigned u = __float_as_uint(f);
  u += 0x7FFFu + ((u >> 16) & 1u);   // RTNE
  return (unsigned short)(u >> 16);
}
__device__ __forceinline__ float bf2f(unsigned short s) {
  return __uint_as_float(((unsigned)s) << 16);
}
// two fp32 -> packed bf16 pair (round-half-up: +0x8000 then take hi16 via
// v_perm). 1.5 VALU ops/element vs ~4 for full RTNE; accuracy slack (absmax
// 0.0625 vs threshold 0.231) absorbs the tie-rounding difference.
__device__ __forceinline__ unsigned bfpack2(float a, float b) {
  unsigned ua = __float_as_uint(a) + 0x8000u;
  unsigned ub = __float_as_uint(b) + 0x8000u;
  return __builtin_amdgcn_perm(ub, ua, 0x07060302u);  // [ub.hi16 : ua.hi16]
}
__device__ __forceinline__ float sigf(float x) {
  return __builtin_amdgcn_rcpf(1.0f + __expf(-x));
}
__device__ __forceinline__ float tanhf_(float x) {
  return 1.0f - 2.0f * __builtin_amdgcn_rcpf(__expf(2.0f * x) + 1.0f);
}
// LDS-only barrier: lgkmcnt(0)+s_barrier, leaves global loads/stores in flight.
__device__ __forceinline__ void barrier_lds() {
  asm volatile("s_waitcnt lgkmcnt(0)\n\ts_barrier" ::: "memory");
}
// async global->LDS, 16B per lane; LDS dst = wave-uniform base + lane*16.
__device__ __forceinline__ void gload_lds16(const void* g, void* l) {
  __builtin_amdgcn_global_load_lds(
      (const __attribute__((address_space(1))) u32t*)g,
      (__attribute__((address_space(3))) u32t*)l, 16, 0, 0);
}
// load one lane's 4 gate-quads (32 B contiguous in the gate-interleaved pre2
// layout) as two dwordx4.
__device__ __forceinline__ void load_pr(const unsigned short* p, ushort4* pr) {
  union { uint4 v; ushort4 s[2]; } a, b;
  a.v = *(const uint4*)p;
  b.v = *(const uint4*)(p + 8);
  pr[0] = a.s[0]; pr[1] = a.s[1]; pr[2] = b.s[0]; pr[3] = b.s[1];
}

// ---------------------------------------------------------------------------
// K0w: W_ih fp32 [512][292] -> Wb bf16 [512][320] (k 292..319 zero-padded).
// 512*40 granules (16B out / 32B in) over 80 blocks.
// ---------------------------------------------------------------------------
__global__ __launch_bounds__(256) void k0w_cvt(
    const float* __restrict__ Wih, unsigned short* __restrict__ Wb) {
  const int g = blockIdx.x * 256 + threadIdx.x;
  const int row = g / 40, s = g % 40;
  float4 a = {0.f, 0.f, 0.f, 0.f}, b = {0.f, 0.f, 0.f, 0.f};
  const float* p = Wih + (size_t)row * IN_ + 8 * s;
  if (s < 36) { a = *(const float4*)p; b = *(const float4*)(p + 4); }
  else if (s == 36) { a = *(const float4*)p; }  // floats 288..291
  uint4 o;
  o.x = bfpack2(a.x, a.y); o.y = bfpack2(a.z, a.w);
  o.z = bfpack2(b.x, b.y); o.w = bfpack2(b.z, b.w);
  *(uint4*)&Wb[(size_t)row * KP_ + 8 * s] = o;
}

// ---------------------------------------------------------------------------
// K1: pre2 = x @ W_ih^T + bias, bf16, gate-interleaved layout:
//   pre2[m*512 + (k>>2)*16 + gate*4 + (k&3)]  (k = cell 0..127, gate 0..3)
// so K2 reads one lane's {i,f,g,o} quads as ONE 32 B load.
// Computed as D = W * x^T per 128j x 128m tile; gate = blockIdx.x.
// Staging: W via async global_load_lds (bf16, double-buffered, prefetched
// 1 iter ahead); x via distance-2 VGPR prefetch + perm-pack cvt.
// ---------------------------------------------------------------------------
__global__ __launch_bounds__(256) void k1_pregemm(
    const float* __restrict__ x, const unsigned short* __restrict__ Wb,
    const float* __restrict__ bih, const float* __restrict__ bhh,
    unsigned short* __restrict__ pre2) {
  __shared__ unsigned short xbt[128 * 32];      // x tile [row][32 bf16]
  __shared__ unsigned short wbt[2][128 * 32];   // W tile, double-buffered
  __shared__ float bias_s[128];

  const int gate = blockIdx.x;
  const int m0 = blockIdx.y * 128;
  const int j0 = gate * 128;
  const int tid = threadIdx.x;
  const int w = tid >> 6;
  const int lane = tid & 63;
  const int l15 = lane & 15;
  const int q = lane >> 4;
  const int jb = (w >> 1) * 64;
  const int mb = (w & 1) * 64;
  const int row = tid >> 1, half = tid & 1;

  if (tid < 128) bias_s[tid] = bih[j0 + tid] + bhh[j0 + tid];

  // x prefetch registers (distance 2) + tail quad
  const float* xrow = x + (size_t)(m0 + row) * IN_ + half * 16;
  float4 xr[4], xn[4], xt = {0.f, 0.f, 0.f, 0.f};
#pragma unroll
  for (int i = 0; i < 4; i++) xr[i] = *(const float4*)(xrow + 4 * i);
#pragma unroll
  for (int i = 0; i < 4; i++) xn[i] = *(const float4*)(xrow + 32 + 4 * i);
  if (half == 0) xt = *(const float4*)(x + (size_t)(m0 + row) * IN_ + 288);

  // async W(0) -> wbt[0]
#pragma unroll
  for (int l = 0; l < 2; l++) {
    const unsigned short* g = Wb + (size_t)(j0 + 32 * w + 16 * l + (lane >> 2)) * KP_
                              + (lane & 3) * 8;
    gload_lds16(g, &wbt[0][(32 * w + 16 * l) * 32]);
  }

  f32x4 acc[4][4];
#pragma unroll
  for (int a = 0; a < 4; a++)
#pragma unroll
    for (int b = 0; b < 4; b++) acc[a][b] = (f32x4){0.f, 0.f, 0.f, 0.f};

#pragma unroll 1
  for (int it = 0; it < 10; it++) {
    barrier_lds();  // prior iter's frag reads complete (lgkm only)
    // stage x bf16 tile from registers
    if (it < 9) {
      uint4 lo, hi;
      lo.x = bfpack2(xr[0].x, xr[0].y); lo.y = bfpack2(xr[0].z, xr[0].w);
      lo.z = bfpack2(xr[1].x, xr[1].y); lo.w = bfpack2(xr[1].z, xr[1].w);
      hi.x = bfpack2(xr[2].x, xr[2].y); hi.y = bfpack2(xr[2].z, xr[2].w);
      hi.z = bfpack2(xr[3].x, xr[3].y); hi.w = bfpack2(xr[3].z, xr[3].w);
      *(uint4*)&xbt[row * 32 + half * 16] = lo;
      *(uint4*)&xbt[row * 32 + half * 16 + 8] = hi;
    } else {
      // tail kk=288: 4 real floats, rest zero
      uint4 z = {0u, 0u, 0u, 0u};
      if (half == 0) {
        uint4 v;
        v.x = bfpack2(xt.x, xt.y); v.y = bfpack2(xt.z, xt.w);
        v.z = 0u; v.w = 0u;
        *(uint4*)&xbt[row * 32] = v;
        *(uint4*)&xbt[row * 32 + 8] = z;
      } else {
        *(uint4*)&xbt[row * 32 + 16] = z;
        *(uint4*)&xbt[row * 32 + 24] = z;
      }
    }
    __syncthreads();  // drains ds_writes + asyncW(it) (issued >=1 iter ago)

    // rotate x prefetch, issue next loads AFTER the vm-drain point
#pragma unroll
    for (int i = 0; i < 4; i++) xr[i] = xn[i];
    if (it < 7) {
#pragma unroll
      for (int i = 0; i < 4; i++)
        xn[i] = *(const float4*)(xrow + 32 * (it + 2) + 4 * i);
    }
    if (it < 9) {
      const int kk = (it + 1) * 32;
      unsigned short* dst = wbt[(it + 1) & 1];
#pragma unroll
      for (int l = 0; l < 2; l++) {
        const unsigned short* g = Wb + (size_t)(j0 + 32 * w + 16 * l + (lane >> 2)) * KP_
                                  + kk + (lane & 3) * 8;
        gload_lds16(g, dst + (32 * w + 16 * l) * 32);
      }
    }

    const unsigned short* wb_ = wbt[it & 1];
    bf16x8 af[4], bfr[4];
#pragma unroll
    for (int s = 0; s < 4; s++)
      af[s] = *(const bf16x8*)&wb_[(jb + 16 * s + l15) * 32 + q * 8];
#pragma unroll
    for (int s = 0; s < 4; s++)
      bfr[s] = *(const bf16x8*)&xbt[(mb + 16 * s + l15) * 32 + q * 8];
#pragma unroll
    for (int js = 0; js < 4; js++)
#pragma unroll
      for (int ms = 0; ms < 4; ms++)
        acc[js][ms] = __builtin_amdgcn_mfma_f32_16x16x32_bf16(
            af[js], bfr[ms], acc[js][ms], 0, 0, 0);
  }

#pragma unroll
  for (int js = 0; js < 4; js++) {
    float4 bv = *(float4*)&bias_s[jb + 16 * js + 4 * q];
    const int kq = (jb >> 2) + 4 * js + q;
#pragma unroll
    for (int ms = 0; ms < 4; ms++) {
      const int m = m0 + mb + 16 * ms + l15;
      uint2 st;
      st.x = bfpack2(acc[js][ms][0] + bv.x, acc[js][ms][1] + bv.y);
      st.y = bfpack2(acc[js][ms][2] + bv.z, acc[js][ms][3] + bv.w);
      *(uint2*)&pre2[((size_t)m << 9) + kq * 16 + gate * 4] = st;
    }
  }
}

// ---------------------------------------------------------------------------
// Segment-scan LSTM (exact for any done; fast because P(reset)=0.5).
// k2a: (bg, chunk) blocks from zero carry; stores outputs from first reset
//      onward; stashes chunk-final (h bf16, c fp32).
// k2b_par: (bg, chunk) blocks recompute only each chunk's prefix from the
//      true carry (= k2a final of prev chunk, exact when prev chunk had >=1
//      reset per batch). Flags chunks with a reset-free batch.
// k2c: sequential guard; exits immediately unless some flag fired.
// ---------------------------------------------------------------------------
__global__ __launch_bounds__(512) void k2a_chunk(
    const unsigned short* __restrict__ pre2, const float* __restrict__ Whh,
    const int* __restrict__ done, unsigned short* __restrict__ hidden,
    unsigned short* __restrict__ hfin, float* __restrict__ cfin) {
  __shared__ unsigned short hs[2][16 * 136];
  __shared__ int dns[LCH * 16];

  const int bg = blockIdx.x & 15;
  const int ck = blockIdx.x >> 4;
  const int t0 = ck * LCH;
  const int tid = threadIdx.x;
  const int w = tid >> 6;
  const int lane = tid & 63;
  const int l15 = lane & 15;
  const int q = lane >> 4;
  const int bglob = bg * 16 + l15;
  const int kcell = 16 * w + 4 * q;
  const int kq16 = (4 * w + q) * 16;

  {
    const int r = tid >> 4, c = tid & 15;
    dns[tid] = done[(size_t)(t0 + r) * B_ + bg * 16 + c];
  }

  bf16x8 wf[4][4];
#pragma unroll
  for (int tI = 0; tI < 4; tI++) {
    const int jg = 16 * (w + 8 * tI) + l15;
#pragma unroll
    for (int kc = 0; kc < 4; kc++) {
      const float* p = Whh + (size_t)jg * H_ + kc * 32 + q * 8;
      float4 u0 = *(const float4*)p;
      float4 u1 = *(const float4*)(p + 4);
      bf16x8 r;
      r[0]=(short)f2bf(u0.x); r[1]=(short)f2bf(u0.y); r[2]=(short)f2bf(u0.z); r[3]=(short)f2bf(u0.w);
      r[4]=(short)f2bf(u1.x); r[5]=(short)f2bf(u1.y); r[6]=(short)f2bf(u1.z); r[7]=(short)f2bf(u1.w);
      wf[tI][kc] = r;
    }
  }

  float c_[4] = {0.f, 0.f, 0.f, 0.f};
  {
    const int b = tid >> 5, k = (tid & 31) * 4;
    *(ushort4*)&hs[0][b * 136 + k] = (ushort4){0, 0, 0, 0};
  }
  bool vld = false;
  __syncthreads();

  ushort4 pr[4], prn[4];
  load_pr(pre2 + ((size_t)t0 * B_ + bglob) * G4_ + kq16, pr);
  load_pr(pre2 + ((size_t)(t0 + 1) * B_ + bglob) * G4_ + kq16, prn);

  ushort4 hw = {0, 0, 0, 0};
#pragma unroll 1
  for (int u = 0; u < LCH; u++) {
    const int t = t0 + u;
    ushort4 pr2[4];
    const int un = (u + 2 < LCH) ? u + 2 : LCH - 1;
    load_pr(pre2 + ((size_t)(t0 + un) * B_ + bglob) * G4_ + kq16, pr2);

    const int dn = dns[u * 16 + l15];
    vld = vld || (dn != 0);

    const unsigned short* hb = hs[u & 1];
    bf16x8 hf[4];
#pragma unroll
    for (int kc = 0; kc < 4; kc++) {
      bf16x8 v = *(const bf16x8*)&hb[l15 * 136 + kc * 32 + q * 8];
      if (dn) v = (bf16x8){0, 0, 0, 0, 0, 0, 0, 0};
      hf[kc] = v;
    }

    f32x4 acc[4];
#pragma unroll
    for (int tI = 0; tI < 4; tI++) acc[tI] = (f32x4){0.f, 0.f, 0.f, 0.f};
#pragma unroll
    for (int tI = 0; tI < 4; tI++)
#pragma unroll
      for (int kc = 0; kc < 4; kc++)
        acc[tI] = __builtin_amdgcn_mfma_f32_16x16x32_bf16(
            wf[tI][kc], hf[kc], acc[tI], 0, 0, 0);

    const float m = dn ? 0.0f : 1.0f;
    float hv[4];
#pragma unroll
    for (int r = 0; r < 4; r++) {
      const float iv = acc[0][r] + bf2f((&pr[0].x)[r]);
      const float fv = acc[1][r] + bf2f((&pr[1].x)[r]);
      const float gv = acc[2][r] + bf2f((&pr[2].x)[r]);
      const float ov = acc[3][r] + bf2f((&pr[3].x)[r]);
      float cc = c_[r] * m;
      cc = sigf(fv) * cc + sigf(iv) * tanhf_(gv);
      c_[r] = cc;
      hv[r] = sigf(ov) * tanhf_(cc);
    }
    uint2 hp = {bfpack2(hv[0], hv[1]), bfpack2(hv[2], hv[3])};
    hw = *(ushort4*)&hp;
    *(uint2*)&hs[(u + 1) & 1][l15 * 136 + kcell] = hp;
    if (vld)
      *(uint2*)&hidden[((size_t)t * B_ + bglob) * H_ + kcell] = hp;
#pragma unroll
    for (int tI = 0; tI < 4; tI++) { pr[tI] = prn[tI]; prn[tI] = pr2[tI]; }
    barrier_lds();
  }

  *(ushort4*)&hfin[((size_t)ck * B_ + bglob) * H_ + kcell] = hw;
  float4 cv = {c_[0], c_[1], c_[2], c_[3]};
  *(float4*)&cfin[((size_t)ck * B_ + bglob) * H_ + kcell] = cv;
}

__global__ __launch_bounds__(512) void k2b_par(
    const unsigned short* __restrict__ pre2, const float* __restrict__ Whh,
    const float* __restrict__ h0, const float* __restrict__ c0,
    const int* __restrict__ done, unsigned short* __restrict__ hidden,
    const unsigned short* __restrict__ hfin, const float* __restrict__ cfin,
    int* __restrict__ needfix) {
  __shared__ unsigned short hs[2][16 * 136];
  __shared__ int dns[LCH * 16];

  const int bg = blockIdx.x & 15;
  const int ck = blockIdx.x >> 4;
  const int t0 = ck * LCH;
  const int tid = threadIdx.x;
  const int w = tid >> 6;
  const int lane = tid & 63;
  const int l15 = lane & 15;
  const int q = lane >> 4;
  const int bglob = bg * 16 + l15;
  const int kcell = 16 * w + 4 * q;
  const int kq16 = (4 * w + q) * 16;

  {
    const int r = tid >> 4, c = tid & 15;
    dns[tid] = done[(size_t)(t0 + r) * B_ + bg * 16 + c];
  }

  bf16x8 wf[4][4];
#pragma unroll
  for (int tI = 0; tI < 4; tI++) {
    const int jg = 16 * (w + 8 * tI) + l15;
#pragma unroll
    for (int kc = 0; kc < 4; kc++) {
      const float* p = Whh + (size_t)jg * H_ + kc * 32 + q * 8;
      float4 u0 = *(const float4*)p;
      float4 u1 = *(const float4*)(p + 4);
      bf16x8 r;
      r[0]=(short)f2bf(u0.x); r[1]=(short)f2bf(u0.y); r[2]=(short)f2bf(u0.z); r[3]=(short)f2bf(u0.w);
      r[4]=(short)f2bf(u1.x); r[5]=(short)f2bf(u1.y); r[6]=(short)f2bf(u1.z); r[7]=(short)f2bf(u1.w);
      wf[tI][kc] = r;
    }
  }

  // true-carry init: ck==0 -> (h0,c0); else k2a finals of ck-1
  float c_[4];
  {
    const int b = tid >> 5, k = (tid & 31) * 4;
    if (ck == 0) {
      float4 hv = *(const float4*)(h0 + (size_t)(bg * 16 + b) * H_ + k);
      uint2 hp = {bfpack2(hv.x, hv.y), bfpack2(hv.z, hv.w)};
      *(uint2*)&hs[0][b * 136 + k] = hp;
      float4 cv = *(const float4*)(c0 + (size_t)bglob * H_ + kcell);
      c_[0] = cv.x; c_[1] = cv.y; c_[2] = cv.z; c_[3] = cv.w;
    } else {
      ushort4 hv = *(const ushort4*)&hfin[((size_t)(ck - 1) * B_ + bg * 16 + b) * H_ + k];
      *(ushort4*)&hs[0][b * 136 + k] = hv;
      float4 cv = *(const float4*)&cfin[((size_t)(ck - 1) * B_ + bglob) * H_ + kcell];
      c_[0] = cv.x; c_[1] = cv.y; c_[2] = cv.z; c_[3] = cv.w;
    }
  }
  int cur = 0;
  bool act = true;
  __syncthreads();

  ushort4 pr[4];
  load_pr(pre2 + ((size_t)t0 * B_ + bglob) * G4_ + kq16, pr);

#pragma unroll 1
  for (int u = 0; u < LCH; u++) {
    const int t = t0 + u;
    const int dn = dns[u * 16 + l15];
    const bool nact = act && (dn == 0);
    if (__ballot(nact) == 0ULL) { act = false; break; }
    act = nact;

    ushort4 prn[4];
    const int un = (u + 1 < LCH) ? u + 1 : LCH - 1;
    load_pr(pre2 + ((size_t)(t0 + un) * B_ + bglob) * G4_ + kq16, prn);

    const unsigned short* hb = hs[cur];
    bf16x8 hf[4];
#pragma unroll
    for (int kc = 0; kc < 4; kc++)
      hf[kc] = *(const bf16x8*)&hb[l15 * 136 + kc * 32 + q * 8];

    f32x4 acc[4];
#pragma unroll
    for (int tI = 0; tI < 4; tI++) acc[tI] = (f32x4){0.f, 0.f, 0.f, 0.f};
#pragma unroll
    for (int tI = 0; tI < 4; tI++)
#pragma unroll
      for (int kc = 0; kc < 4; kc++)
        acc[tI] = __builtin_amdgcn_mfma_f32_16x16x32_bf16(
            wf[tI][kc], hf[kc], acc[tI], 0, 0, 0);

    float hv[4];
#pragma unroll
    for (int r = 0; r < 4; r++) {
      const float iv = acc[0][r] + bf2f((&pr[0].x)[r]);
      const float fv = acc[1][r] + bf2f((&pr[1].x)[r]);
      const float gv = acc[2][r] + bf2f((&pr[2].x)[r]);
      const float ov = acc[3][r] + bf2f((&pr[3].x)[r]);
      float cc = sigf(fv) * c_[r] + sigf(iv) * tanhf_(gv);
      c_[r] = cc;
      hv[r] = sigf(ov) * tanhf_(cc);
    }
    uint2 hp = {bfpack2(hv[0], hv[1]), bfpack2(hv[2], hv[3])};
    *(uint2*)&hs[cur ^ 1][l15 * 136 + kcell] = hp;
    if (act)
      *(uint2*)&hidden[((size_t)t * B_ + bglob) * H_ + kcell] = hp;
#pragma unroll
    for (int tI = 0; tI < 4; tI++) pr[tI] = prn[tI];
    barrier_lds();
    cur ^= 1;
  }

  // flag = some batch never reset in this chunk (its carry-out chain is wrong)
  if (tid == 0) needfix[blockIdx.x] = (__ballot(act) != 0ULL) ? 1 : 0;
}

// Sequential guard: exact fallback, expected to exit immediately.
__global__ __launch_bounds__(512) void k2c_guard(
    const unsigned short* __restrict__ pre2, const float* __restrict__ Whh,
    const float* __restrict__ h0, const float* __restrict__ c0,
    const int* __restrict__ done, unsigned short* __restrict__ hidden,
    const unsigned short* __restrict__ hfin, const float* __restrict__ cfin,
    const int* __restrict__ needfix) {
  const int bg = blockIdx.x;
  bool dirty = false;
  for (int c2 = 0; c2 < NCH - 1; c2++) dirty |= (needfix[c2 * 16 + bg] != 0);
  if (!dirty) return;

  __shared__ unsigned short hs[2][16 * 136];
  __shared__ int dns[T_ * 16];

  const int tid = threadIdx.x;
  const int w = tid >> 6;
  const int lane = tid & 63;
  const int l15 = lane & 15;
  const int q = lane >> 4;
  const int bglob = bg * 16 + l15;
  const int kcell = 16 * w + 4 * q;
  const int kq16 = (4 * w + q) * 16;

  {
    const int* p = done + (size_t)tid * B_ + bg * 16;
    *(int4*)&dns[tid * 16]      = *(const int4*)(p);
    *(int4*)&dns[tid * 16 + 4]  = *(const int4*)(p + 4);
    *(int4*)&dns[tid * 16 + 8]  = *(const int4*)(p + 8);
    *(int4*)&dns[tid * 16 + 12] = *(const int4*)(p + 12);
  }

  bf16x8 wf[4][4];
#pragma unroll
  for (int tI = 0; tI < 4; tI++) {
    const int jg = 16 * (w + 8 * tI) + l15;
#pragma unroll
    for (int kc = 0; kc < 4; kc++) {
      const float* p = Whh + (size_t)jg * H_ + kc * 32 + q * 8;
      float4 u0 = *(const float4*)p;
      float4 u1 = *(const float4*)(p + 4);
      bf16x8 r;
      r[0]=(short)f2bf(u0.x); r[1]=(short)f2bf(u0.y); r[2]=(short)f2bf(u0.z); r[3]=(short)f2bf(u0.w);
      r[4]=(short)f2bf(u1.x); r[5]=(short)f2bf(u1.y); r[6]=(short)f2bf(u1.z); r[7]=(short)f2bf(u1.w);
      wf[tI][kc] = r;
    }
  }

  float c_[4];
  {
    float4 cv = *(const float4*)(c0 + (size_t)bglob * H_ + kcell);
    c_[0] = cv.x; c_[1] = cv.y; c_[2] = cv.z; c_[3] = cv.w;
    const int b = tid >> 5, k = (tid & 31) * 4;
    float4 hv = *(const float4*)(h0 + (size_t)(bg * 16 + b) * H_ + k);
    uint2 hp = {bfpack2(hv.x, hv.y), bfpack2(hv.z, hv.w)};
    *(uint2*)&hs[0][b * 136 + k] = hp;
  }
  int cur = 0;
  __syncthreads();

#pragma unroll 1
  for (int ck = 0; ck < NCH; ck++) {
    const int t0 = ck * LCH;
    bool act = true;

    ushort4 pr[4];
    load_pr(pre2 + ((size_t)t0 * B_ + bglob) * G4_ + kq16, pr);

#pragma unroll 1
    for (int u = 0; u < LCH; u++) {
      const int t = t0 + u;
      const int dn = dns[t * 16 + l15];
      const bool nact = act && (dn == 0);
      if (__ballot(nact) == 0ULL) { act = false; break; }
      act = nact;

      ushort4 prn[4];
      const int un = (u + 1 < LCH) ? u + 1 : LCH - 1;
      load_pr(pre2 + ((size_t)(t0 + un) * B_ + bglob) * G4_ + kq16, prn);

      const unsigned short* hb = hs[cur];
      bf16x8 hf[4];
#pragma unroll
      for (int kc = 0; kc < 4; kc++)
        hf[kc] = *(const bf16x8*)&hb[l15 * 136 + kc * 32 + q * 8];

      f32x4 acc[4];
#pragma unroll
      for (int tI = 0; tI < 4; tI++) acc[tI] = (f32x4){0.f, 0.f, 0.f, 0.f};
#pragma unroll
      for (int tI = 0; tI < 4; tI++)
#pragma unroll
        for (int kc = 0; kc < 4; kc++)
          acc[tI] = __builtin_amdgcn_mfma_f32_16x16x32_bf16(
              wf[tI][kc], hf[kc], acc[tI], 0, 0, 0);

      float hv[4];
#pragma unroll
      for (int r = 0; r < 4; r++) {
        const float iv = acc[0][r] + bf2f((&pr[0].x)[r]);
        const float fv = acc[1][r] + bf2f((&pr[1].x)[r]);
        const float gv = acc[2][r] + bf2f((&pr[2].x)[r]);
        const float ov = acc[3][r] + bf2f((&pr[3].x)[r]);
        float cc = sigf(fv) * c_[r] + sigf(iv) * tanhf_(gv);
        c_[r] = cc;
        hv[r] = sigf(ov) * tanhf_(cc);
      }
      uint2 hp = {bfpack2(hv[0], hv[1]), bfpack2(hv[2], hv[3])};
      *(uint2*)&hs[cur ^ 1][l15 * 136 + kcell] = hp;
      if (act)
        *(uint2*)&hidden[((size_t)t * B_ + bglob) * H_ + kcell] = hp;
#pragma unroll
      for (int tI = 0; tI < 4; tI++) pr[tI] = prn[tI];
      barrier_lds();
      cur ^= 1;
    }

    if (!act) {
      ushort4 hv = *(const ushort4*)&hfin[((size_t)ck * B_ + bglob) * H_ + kcell];
      float4 cv = *(const float4*)&cfin[((size_t)ck * B_ + bglob) * H_ + kcell];
      c_[0] = cv.x; c_[1] = cv.y; c_[2] = cv.z; c_[3] = cv.w;
      *(ushort4*)&hs[cur][l15 * 136 + kcell] = hv;
    }
    barrier_lds();
  }
}

// ---------------------------------------------------------------------------
// K3: out[T*B][13] = hidden @ [W_pi; W_v]^T + [b_pi; b_v]   (unchanged)
// ---------------------------------------------------------------------------
__global__ __launch_bounds__(256) void k3_head(
    const unsigned short* __restrict__ hidden, const float* __restrict__ Wpi,
    const float* __restrict__ bpi, const float* __restrict__ Wv,
    const float* __restrict__ bv, float* __restrict__ out) {
  __shared__ unsigned short hs3[64 * 136];
  __shared__ float bias_s[16];

  const int tid = threadIdx.x;
  const int w = tid >> 6;
  const int lane = tid & 63;
  const int l15 = lane & 15;
  const int q = lane >> 4;
  const int m0 = blockIdx.x * 64;

  if (tid < 16) bias_s[tid] = (tid < 12) ? bpi[tid] : ((tid == 12) ? bv[0] : 0.f);

  bf16x8 wf3[4];
#pragma unroll
  for (int kc = 0; kc < 4; kc++) {
    float4 u0 = {0.f, 0.f, 0.f, 0.f}, u1 = {0.f, 0.f, 0.f, 0.f};
    if (l15 < 12) {
      const float* p = Wpi + (size_t)l15 * H_ + kc * 32 + q * 8;
      u0 = *(const float4*)p; u1 = *(const float4*)(p + 4);
    } else if (l15 == 12) {
      const float* p = Wv + kc * 32 + q * 8;
      u0 = *(const float4*)p; u1 = *(const float4*)(p + 4);
    }
    bf16x8 r;
    r[0]=(short)f2bf(u0.x); r[1]=(short)f2bf(u0.y); r[2]=(short)f2bf(u0.z); r[3]=(short)f2bf(u0.w);
    r[4]=(short)f2bf(u1.x); r[5]=(short)f2bf(u1.y); r[6]=(short)f2bf(u1.z); r[7]=(short)f2bf(u1.w);
    wf3[kc] = r;
  }

  {
    const int row = tid >> 2, ks = (tid & 3) * 32;
    const unsigned short* p = hidden + (size_t)(m0 + row) * H_ + ks;
#pragma unroll
    for (int i = 0; i < 4; i++)
      *(uint4*)&hs3[row * 136 + ks + i * 8] = *(const uint4*)(p + i * 8);
  }
  __syncthreads();

  f32x4 acc = (f32x4){0.f, 0.f, 0.f, 0.f};
#pragma unroll
  for (int kc = 0; kc < 4; kc++) {
    bf16x8 hf = *(bf16x8*)&hs3[(16 * w + l15) * 136 + kc * 32 + q * 8];
    acc = __builtin_amdgcn_mfma_f32_16x16x32_bf16(wf3[kc], hf, acc, 0, 0, 0);
  }

  const float4 bb = *(float4*)&bias_s[4 * q];
  const int m = m0 + 16 * w + l15;
  const size_t ro = (size_t)m * 13;
  float v0 = acc[0] + bb.x, v1 = acc[1] + bb.y, v2 = acc[2] + bb.z, v3 = acc[3] + bb.w;
  if (q < 3) {
    out[ro + 4 * q + 0] = v0;
    out[ro + 4 * q + 1] = v1;
    out[ro + 4 * q + 2] = v2;
    out[ro + 4 * q + 3] = v3;
  } else {
    out[ro + 12] = v0;
  }
}

// ---------------------------------------------------------------------------
// Workspace (ws, 167.8 MB — same footprint that already passed):
//   pre2   bf16 [131072][512] : 134,217,728 B @ 0   (gate-interleaved layout)
//   hidden bf16 [131072][128] :  33,554,432 B @ 134,217,728
// Scratch in d_out (6.8 MB, overwritten by K3 at the end):
//   Wb bf16 [512][320] @ 0        (written K0w, read K1)
//   hfin @ 1 MB, cfin @ 2 MB, needfix @ 4 MB (written k2a/k2b_par)
// ---------------------------------------------------------------------------
extern "C" void kernel_launch(void* const* d_in, const int* in_sizes, int n_in,
                              void* d_out, int out_size, void* d_ws, size_t ws_size,
                              hipStream_t stream) {
  const float* x    = (const float*)d_in[0];
  const int* done   = (const int*)d_in[1];
  const float* h0   = (const float*)d_in[2];
  const float* c0   = (const float*)d_in[3];
  const float* Wih  = (const float*)d_in[4];
  const float* Whh  = (const float*)d_in[5];
  const float* bih  = (const float*)d_in[6];
  const float* bhh  = (const float*)d_in[7];
  const float* Wpi  = (const float*)d_in[8];
  const float* bpi  = (const float*)d_in[9];
  const float* Wv   = (const float*)d_in[10];
  const float* bv   = (const float*)d_in[11];
  (void)in_sizes; (void)n_in; (void)out_size; (void)ws_size;

  unsigned short* pre2 = (unsigned short*)d_ws;
  unsigned short* hidden = pre2 + (size_t)TB_ * G4_;
  unsigned short* Wb   = (unsigned short*)d_out;
  unsigned short* hfin = (unsigned short*)((char*)d_out + (1u << 20));
  float* cfin          = (float*)((char*)d_out + (2u << 20));
  int* needfix         = (int*)((char*)d_out + (4u << 20));
  float* out = (float*)d_out;

  k0w_cvt<<<80, 256, 0, stream>>>(Wih, Wb);
  k1_pregemm<<<dim3(4, TB_ / 128), 256, 0, stream>>>(x, Wb, bih, bhh, pre2);
  k2a_chunk<<<256, 512, 0, stream>>>(pre2, Whh, done, hidden, hfin, cfin);
  k2b_par<<<256, 512, 0, stream>>>(pre2, Whh, h0, c0, done, hidden, hfin, cfin, needfix);
  k2c_guard<<<16, 512, 0, stream>>>(pre2, Whh, h0, c0, done, hidden, hfin, cfin, needfix);
  k3_head<<<TB_ / 64, 256, 0, stream>>>(hidden, Wpi, bpi, Wv, bv, out);
}

// Round 5
// 431.204 us; speedup vs baseline: 2.7692x; 1.1748x over previous
//
#include <hip/hip_runtime.h>
#include <stdint.h>
#include <stddef.h>

// Problem constants
#define T_ 512
#define B_ 256
#define IN_ 292
#define H_ 128
#define G4_ 512     // 4*H
#define TB_ 131072  // T_*B_
#define LCH 32      // time-chunk length for the segment scan
#define NCH 16      // number of chunks (T_/LCH)
#define KP_ 320     // K padded to 10*32

typedef short bf16x8 __attribute__((ext_vector_type(8)));
typedef float f32x4 __attribute__((ext_vector_type(4)));

__device__ __forceinline__ unsigned short f2bf(float f) {
  unsigned u = __float_as_uint(f);
  u += 0x7FFFu + ((u >> 16) & 1u);   // RTNE
  return (unsigned short)(u >> 16);
}
__device__ __forceinline__ float bf2f(unsigned short s) {
  return __uint_as_float(((unsigned)s) << 16);
}
// two fp32 -> packed bf16 pair (round-half-up). 1.5 VALU ops/elem.
__device__ __forceinline__ unsigned bfpack2(float a, float b) {
  unsigned ua = __float_as_uint(a) + 0x8000u;
  unsigned ub = __float_as_uint(b) + 0x8000u;
  return __builtin_amdgcn_perm(ub, ua, 0x07060302u);  // [ub.hi16 : ua.hi16]
}
__device__ __forceinline__ float sigf(float x) {
  return __builtin_amdgcn_rcpf(1.0f + __expf(-x));
}
__device__ __forceinline__ float tanhf_(float x) {
  return 1.0f - 2.0f * __builtin_amdgcn_rcpf(__expf(2.0f * x) + 1.0f);
}
// LDS-only barrier: lgkmcnt(0)+s_barrier, leaves global loads/stores in flight.
__device__ __forceinline__ void barrier_lds() {
  asm volatile("s_waitcnt lgkmcnt(0)\n\ts_barrier" ::: "memory");
}
// load one lane's 4 cell-quads (32 B contiguous): pr[r] = {i,f,g,o} of cell r.
__device__ __forceinline__ void load_pr(const unsigned short* p, ushort4* pr) {
  union { uint4 v; ushort4 s[2]; } a, b;
  a.v = *(const uint4*)p;
  b.v = *(const uint4*)(p + 8);
  pr[0] = a.s[0]; pr[1] = a.s[1]; pr[2] = b.s[0]; pr[3] = b.s[1];
}

// ---------------------------------------------------------------------------
// K0w: W_ih fp32 [512][292] -> Wb2 bf16 [512][320], ROW-REORDERED so that
// row jj = W_ih row (jj&3)*128 + (jj>>2)   (jj = cell*4 + gate).
// A plain GEMM over jj then emits pre2 in the cell-major-quad layout K2 reads
// with one 32B load. Also emits reordered bias2[jj] (fp32).
// ---------------------------------------------------------------------------
__global__ __launch_bounds__(256) void k0w_cvt(
    const float* __restrict__ Wih, const float* __restrict__ bih,
    const float* __restrict__ bhh, unsigned short* __restrict__ Wb,
    float* __restrict__ bias2) {
  const int g = blockIdx.x * 256 + threadIdx.x;
  const int jj = g / 40, s = g % 40;
  const int src = (jj & 3) * 128 + (jj >> 2);
  if (g < 512) {
    const int sb = (g & 3) * 128 + (g >> 2);
    bias2[g] = bih[sb] + bhh[sb];
  }
  float4 a = {0.f, 0.f, 0.f, 0.f}, b = {0.f, 0.f, 0.f, 0.f};
  const float* p = Wih + (size_t)src * IN_ + 8 * s;
  if (s < 36) { a = *(const float4*)p; b = *(const float4*)(p + 4); }
  else if (s == 36) { a = *(const float4*)p; }  // floats 288..291
  uint4 o;
  o.x = bfpack2(a.x, a.y); o.y = bfpack2(a.z, a.w);
  o.z = bfpack2(b.x, b.y); o.w = bfpack2(b.z, b.w);
  *(uint4*)&Wb[(size_t)jj * KP_ + 8 * s] = o;
}

// ---------------------------------------------------------------------------
// K1: pre2[m][jj] (bf16) = x @ Wb2^T + bias2, jj = cell*4+gate.
// Grid: 1024 m-tiles of 128; block 512 thr (8 waves), wave w owns jj range
// [64w, 64w+64) x all 128 m  (acc 4x8 f32x4 = 128 VGPR).
//  - W frags: DIRECT global->register loads (Wb2 = 320 KB, L2-hot;
//    compiler-managed fine-grained vmcnt -> no barrier interaction).
//  - x: fp32 global->regs (3-stage ring, ld->use ~2 iters), pack AFTER the
//    MFMAs, ds_write to double-buffered LDS tile; barrier = lgkm-only.
//  - x read ONCE (153 MB); every 1024B output row fully written by one block
//    (full-line writes, no amplification).
// ---------------------------------------------------------------------------
__global__ __launch_bounds__(512, 2) void k1_pregemm(
    const float* __restrict__ x, const unsigned short* __restrict__ Wb,
    const float* __restrict__ bias2, unsigned short* __restrict__ pre2) {
  __shared__ unsigned short xt[2][128 * 32];  // [buf][m-row][32 bf16] = 16 KB

  const int m0 = blockIdx.x * 128;
  const int tid = threadIdx.x;
  const int w = tid >> 6;
  const int lane = tid & 63;
  const int l15 = lane & 15;
  const int q = lane >> 4;

  // per-lane x staging slice: row = w*16 + (lane>>2), cols (lane&3)*8 .. +7
  const int xrow = w * 16 + (lane >> 2);
  const int xcol = (lane & 3) * 8;
  const float* xbase = x + (size_t)(m0 + xrow) * IN_;

  f32x4 acc[4][8];
#pragma unroll
  for (int s = 0; s < 4; s++)
#pragma unroll
    for (int ms = 0; ms < 8; ms++) acc[s][ms] = (f32x4){0.f, 0.f, 0.f, 0.f};

  // 3-stage x register ring: stage t%3 holds tile t (2 float4 = 8 floats)
  float4 xst[3][2];
#pragma unroll
  for (int t = 0; t < 3; t++) {
    xst[t][0] = *(const float4*)(xbase + 32 * t + xcol);
    xst[t][1] = *(const float4*)(xbase + 32 * t + xcol + 4);
  }
  // W frags tile 0 (jj rows w*64+16s+l15)
  bf16x8 af[4];
#pragma unroll
  for (int s = 0; s < 4; s++)
    af[s] = *(const bf16x8*)&Wb[(size_t)(w * 64 + 16 * s + l15) * KP_ + q * 8];

  // pack tile 0 -> xt[0]
  {
    uint4 v;
    v.x = bfpack2(xst[0][0].x, xst[0][0].y); v.y = bfpack2(xst[0][0].z, xst[0][0].w);
    v.z = bfpack2(xst[0][1].x, xst[0][1].y); v.w = bfpack2(xst[0][1].z, xst[0][1].w);
    *(uint4*)&xt[0][xrow * 32 + xcol] = v;
  }
  barrier_lds();

#pragma unroll
  for (int it = 0; it < 10; it++) {
    // prefetch W frags for tile it+1
    bf16x8 afn[4];
    if (it < 9) {
      const int kk = 32 * (it + 1);
#pragma unroll
      for (int s = 0; s < 4; s++)
        afn[s] = *(const bf16x8*)&Wb[(size_t)(w * 64 + 16 * s + l15) * KP_ + kk + q * 8];
    }
    // issue x loads for tile it+3 into ring stage it%3
    if (it + 3 <= 9) {
      const int tt = it + 3;
      if (tt < 9) {
        xst[it % 3][0] = *(const float4*)(xbase + 32 * tt + xcol);
        xst[it % 3][1] = *(const float4*)(xbase + 32 * tt + xcol + 4);
      } else {  // tail tile: cols 288..291 valid only
        float4 z = {0.f, 0.f, 0.f, 0.f};
        xst[it % 3][0] = (xcol == 0) ? *(const float4*)(xbase + 288) : z;
        xst[it % 3][1] = z;
      }
    }
    // fragments + MFMA on tile it
    const unsigned short* xb = xt[it & 1];
    bf16x8 bfr[8];
#pragma unroll
    for (int ms = 0; ms < 8; ms++)
      bfr[ms] = *(const bf16x8*)&xb[(16 * ms + l15) * 32 + q * 8];
#pragma unroll
    for (int s = 0; s < 4; s++)
#pragma unroll
      for (int ms = 0; ms < 8; ms++)
        acc[s][ms] = __builtin_amdgcn_mfma_f32_16x16x32_bf16(
            af[s], bfr[ms], acc[s][ms], 0, 0, 0);
    // pack tile it+1 (regs loaded 2 iters ago -> latency covered by MFMAs)
    if (it < 9) {
      const float4* xs = xst[(it + 1) % 3];
      uint4 v;
      v.x = bfpack2(xs[0].x, xs[0].y); v.y = bfpack2(xs[0].z, xs[0].w);
      v.z = bfpack2(xs[1].x, xs[1].y); v.w = bfpack2(xs[1].z, xs[1].w);
      *(uint4*)&xt[(it + 1) & 1][xrow * 32 + xcol] = v;
    }
#pragma unroll
    for (int s = 0; s < 4; s++) af[s] = afn[s];
    barrier_lds();
  }

  // epilogue: + bias2[jj], pack, store (full-line coverage per block)
#pragma unroll
  for (int s = 0; s < 4; s++) {
    const int jjb = w * 64 + 16 * s + 4 * q;
    const float4 bb = *(const float4*)&bias2[jjb];
#pragma unroll
    for (int ms = 0; ms < 8; ms++) {
      const int m = m0 + 16 * ms + l15;
      uint2 st;
      st.x = bfpack2(acc[s][ms][0] + bb.x, acc[s][ms][1] + bb.y);
      st.y = bfpack2(acc[s][ms][2] + bb.z, acc[s][ms][3] + bb.w);
      *(uint2*)&pre2[((size_t)m << 9) + jjb] = st;
    }
  }
}

// ---------------------------------------------------------------------------
// Segment-scan LSTM (exact for any done; fast because P(reset)=0.5).
// pre2 layout: element m*512 + cell*4 + gate -> one 32B load per lane gives
// pr[r] = {i,f,g,o} of cell kcell+r.
// ---------------------------------------------------------------------------
__global__ __launch_bounds__(512) void k2a_chunk(
    const unsigned short* __restrict__ pre2, const float* __restrict__ Whh,
    const int* __restrict__ done, unsigned short* __restrict__ hidden,
    unsigned short* __restrict__ hfin, float* __restrict__ cfin) {
  __shared__ unsigned short hs[2][16 * 136];
  __shared__ int dns[LCH * 16];

  const int bg = blockIdx.x & 15;
  const int ck = blockIdx.x >> 4;
  const int t0 = ck * LCH;
  const int tid = threadIdx.x;
  const int w = tid >> 6;
  const int lane = tid & 63;
  const int l15 = lane & 15;
  const int q = lane >> 4;
  const int bglob = bg * 16 + l15;
  const int kcell = 16 * w + 4 * q;
  const int kq16 = kcell * 4;  // element offset of this lane's 4 cell-quads

  {
    const int r = tid >> 4, c = tid & 15;
    dns[tid] = done[(size_t)(t0 + r) * B_ + bg * 16 + c];
  }

  bf16x8 wf[4][4];
#pragma unroll
  for (int tI = 0; tI < 4; tI++) {
    const int jg = 16 * (w + 8 * tI) + l15;
#pragma unroll
    for (int kc = 0; kc < 4; kc++) {
      const float* p = Whh + (size_t)jg * H_ + kc * 32 + q * 8;
      float4 u0 = *(const float4*)p;
      float4 u1 = *(const float4*)(p + 4);
      bf16x8 r;
      r[0]=(short)f2bf(u0.x); r[1]=(short)f2bf(u0.y); r[2]=(short)f2bf(u0.z); r[3]=(short)f2bf(u0.w);
      r[4]=(short)f2bf(u1.x); r[5]=(short)f2bf(u1.y); r[6]=(short)f2bf(u1.z); r[7]=(short)f2bf(u1.w);
      wf[tI][kc] = r;
    }
  }

  float c_[4] = {0.f, 0.f, 0.f, 0.f};
  {
    const int b = tid >> 5, k = (tid & 31) * 4;
    *(ushort4*)&hs[0][b * 136 + k] = (ushort4){0, 0, 0, 0};
  }
  bool vld = false;
  __syncthreads();

  ushort4 pr[4], prn[4];
  load_pr(pre2 + ((size_t)t0 * B_ + bglob) * G4_ + kq16, pr);
  load_pr(pre2 + ((size_t)(t0 + 1) * B_ + bglob) * G4_ + kq16, prn);

  ushort4 hw = {0, 0, 0, 0};
#pragma unroll 1
  for (int u = 0; u < LCH; u++) {
    const int t = t0 + u;
    ushort4 pr2[4];
    const int un = (u + 2 < LCH) ? u + 2 : LCH - 1;
    load_pr(pre2 + ((size_t)(t0 + un) * B_ + bglob) * G4_ + kq16, pr2);

    const int dn = dns[u * 16 + l15];
    vld = vld || (dn != 0);

    const unsigned short* hb = hs[u & 1];
    bf16x8 hf[4];
#pragma unroll
    for (int kc = 0; kc < 4; kc++) {
      bf16x8 v = *(const bf16x8*)&hb[l15 * 136 + kc * 32 + q * 8];
      if (dn) v = (bf16x8){0, 0, 0, 0, 0, 0, 0, 0};
      hf[kc] = v;
    }

    f32x4 acc[4];
#pragma unroll
    for (int tI = 0; tI < 4; tI++) acc[tI] = (f32x4){0.f, 0.f, 0.f, 0.f};
#pragma unroll
    for (int tI = 0; tI < 4; tI++)
#pragma unroll
      for (int kc = 0; kc < 4; kc++)
        acc[tI] = __builtin_amdgcn_mfma_f32_16x16x32_bf16(
            wf[tI][kc], hf[kc], acc[tI], 0, 0, 0);

    const float m = dn ? 0.0f : 1.0f;
    float hv[4];
#pragma unroll
    for (int r = 0; r < 4; r++) {
      const float iv = acc[0][r] + bf2f(pr[r].x);
      const float fv = acc[1][r] + bf2f(pr[r].y);
      const float gv = acc[2][r] + bf2f(pr[r].z);
      const float ov = acc[3][r] + bf2f(pr[r].w);
      float cc = c_[r] * m;
      cc = sigf(fv) * cc + sigf(iv) * tanhf_(gv);
      c_[r] = cc;
      hv[r] = sigf(ov) * tanhf_(cc);
    }
    uint2 hp = {bfpack2(hv[0], hv[1]), bfpack2(hv[2], hv[3])};
    hw = *(ushort4*)&hp;
    *(uint2*)&hs[(u + 1) & 1][l15 * 136 + kcell] = hp;
    if (vld)
      *(uint2*)&hidden[((size_t)t * B_ + bglob) * H_ + kcell] = hp;
#pragma unroll
    for (int tI = 0; tI < 4; tI++) { pr[tI] = prn[tI]; prn[tI] = pr2[tI]; }
    barrier_lds();
  }

  *(ushort4*)&hfin[((size_t)ck * B_ + bglob) * H_ + kcell] = hw;
  float4 cv = {c_[0], c_[1], c_[2], c_[3]};
  *(float4*)&cfin[((size_t)ck * B_ + bglob) * H_ + kcell] = cv;
}

__global__ __launch_bounds__(512) void k2b_par(
    const unsigned short* __restrict__ pre2, const float* __restrict__ Whh,
    const float* __restrict__ h0, const float* __restrict__ c0,
    const int* __restrict__ done, unsigned short* __restrict__ hidden,
    const unsigned short* __restrict__ hfin, const float* __restrict__ cfin,
    int* __restrict__ needfix) {
  __shared__ unsigned short hs[2][16 * 136];
  __shared__ int dns[LCH * 16];

  const int bg = blockIdx.x & 15;
  const int ck = blockIdx.x >> 4;
  const int t0 = ck * LCH;
  const int tid = threadIdx.x;
  const int w = tid >> 6;
  const int lane = tid & 63;
  const int l15 = lane & 15;
  const int q = lane >> 4;
  const int bglob = bg * 16 + l15;
  const int kcell = 16 * w + 4 * q;
  const int kq16 = kcell * 4;

  {
    const int r = tid >> 4, c = tid & 15;
    dns[tid] = done[(size_t)(t0 + r) * B_ + bg * 16 + c];
  }

  bf16x8 wf[4][4];
#pragma unroll
  for (int tI = 0; tI < 4; tI++) {
    const int jg = 16 * (w + 8 * tI) + l15;
#pragma unroll
    for (int kc = 0; kc < 4; kc++) {
      const float* p = Whh + (size_t)jg * H_ + kc * 32 + q * 8;
      float4 u0 = *(const float4*)p;
      float4 u1 = *(const float4*)(p + 4);
      bf16x8 r;
      r[0]=(short)f2bf(u0.x); r[1]=(short)f2bf(u0.y); r[2]=(short)f2bf(u0.z); r[3]=(short)f2bf(u0.w);
      r[4]=(short)f2bf(u1.x); r[5]=(short)f2bf(u1.y); r[6]=(short)f2bf(u1.z); r[7]=(short)f2bf(u1.w);
      wf[tI][kc] = r;
    }
  }

  float c_[4];
  {
    const int b = tid >> 5, k = (tid & 31) * 4;
    if (ck == 0) {
      float4 hv = *(const float4*)(h0 + (size_t)(bg * 16 + b) * H_ + k);
      uint2 hp = {bfpack2(hv.x, hv.y), bfpack2(hv.z, hv.w)};
      *(uint2*)&hs[0][b * 136 + k] = hp;
      float4 cv = *(const float4*)(c0 + (size_t)bglob * H_ + kcell);
      c_[0] = cv.x; c_[1] = cv.y; c_[2] = cv.z; c_[3] = cv.w;
    } else {
      ushort4 hv = *(const ushort4*)&hfin[((size_t)(ck - 1) * B_ + bg * 16 + b) * H_ + k];
      *(ushort4*)&hs[0][b * 136 + k] = hv;
      float4 cv = *(const float4*)&cfin[((size_t)(ck - 1) * B_ + bglob) * H_ + kcell];
      c_[0] = cv.x; c_[1] = cv.y; c_[2] = cv.z; c_[3] = cv.w;
    }
  }
  int cur = 0;
  bool act = true;
  __syncthreads();

  ushort4 pr[4];
  load_pr(pre2 + ((size_t)t0 * B_ + bglob) * G4_ + kq16, pr);

#pragma unroll 1
  for (int u = 0; u < LCH; u++) {
    const int t = t0 + u;
    const int dn = dns[u * 16 + l15];
    const bool nact = act && (dn == 0);
    if (__ballot(nact) == 0ULL) { act = false; break; }
    act = nact;

    ushort4 prn[4];
    const int un = (u + 1 < LCH) ? u + 1 : LCH - 1;
    load_pr(pre2 + ((size_t)(t0 + un) * B_ + bglob) * G4_ + kq16, prn);

    const unsigned short* hb = hs[cur];
    bf16x8 hf[4];
#pragma unroll
    for (int kc = 0; kc < 4; kc++)
      hf[kc] = *(const bf16x8*)&hb[l15 * 136 + kc * 32 + q * 8];

    f32x4 acc[4];
#pragma unroll
    for (int tI = 0; tI < 4; tI++) acc[tI] = (f32x4){0.f, 0.f, 0.f, 0.f};
#pragma unroll
    for (int tI = 0; tI < 4; tI++)
#pragma unroll
      for (int kc = 0; kc < 4; kc++)
        acc[tI] = __builtin_amdgcn_mfma_f32_16x16x32_bf16(
            wf[tI][kc], hf[kc], acc[tI], 0, 0, 0);

    float hv[4];
#pragma unroll
    for (int r = 0; r < 4; r++) {
      const float iv = acc[0][r] + bf2f(pr[r].x);
      const float fv = acc[1][r] + bf2f(pr[r].y);
      const float gv = acc[2][r] + bf2f(pr[r].z);
      const float ov = acc[3][r] + bf2f(pr[r].w);
      float cc = sigf(fv) * c_[r] + sigf(iv) * tanhf_(gv);
      c_[r] = cc;
      hv[r] = sigf(ov) * tanhf_(cc);
    }
    uint2 hp = {bfpack2(hv[0], hv[1]), bfpack2(hv[2], hv[3])};
    *(uint2*)&hs[cur ^ 1][l15 * 136 + kcell] = hp;
    if (act)
      *(uint2*)&hidden[((size_t)t * B_ + bglob) * H_ + kcell] = hp;
#pragma unroll
    for (int tI = 0; tI < 4; tI++) pr[tI] = prn[tI];
    barrier_lds();
    cur ^= 1;
  }

  if (tid == 0) needfix[blockIdx.x] = (__ballot(act) != 0ULL) ? 1 : 0;
}

// Sequential guard: exact fallback, expected to exit immediately.
__global__ __launch_bounds__(512) void k2c_guard(
    const unsigned short* __restrict__ pre2, const float* __restrict__ Whh,
    const float* __restrict__ h0, const float* __restrict__ c0,
    const int* __restrict__ done, unsigned short* __restrict__ hidden,
    const unsigned short* __restrict__ hfin, const float* __restrict__ cfin,
    const int* __restrict__ needfix) {
  const int bg = blockIdx.x;
  bool dirty = false;
  for (int c2 = 0; c2 < NCH - 1; c2++) dirty |= (needfix[c2 * 16 + bg] != 0);
  if (!dirty) return;

  __shared__ unsigned short hs[2][16 * 136];
  __shared__ int dns[T_ * 16];

  const int tid = threadIdx.x;
  const int w = tid >> 6;
  const int lane = tid & 63;
  const int l15 = lane & 15;
  const int q = lane >> 4;
  const int bglob = bg * 16 + l15;
  const int kcell = 16 * w + 4 * q;
  const int kq16 = kcell * 4;

  {
    const int* p = done + (size_t)tid * B_ + bg * 16;
    *(int4*)&dns[tid * 16]      = *(const int4*)(p);
    *(int4*)&dns[tid * 16 + 4]  = *(const int4*)(p + 4);
    *(int4*)&dns[tid * 16 + 8]  = *(const int4*)(p + 8);
    *(int4*)&dns[tid * 16 + 12] = *(const int4*)(p + 12);
  }

  bf16x8 wf[4][4];
#pragma unroll
  for (int tI = 0; tI < 4; tI++) {
    const int jg = 16 * (w + 8 * tI) + l15;
#pragma unroll
    for (int kc = 0; kc < 4; kc++) {
      const float* p = Whh + (size_t)jg * H_ + kc * 32 + q * 8;
      float4 u0 = *(const float4*)p;
      float4 u1 = *(const float4*)(p + 4);
      bf16x8 r;
      r[0]=(short)f2bf(u0.x); r[1]=(short)f2bf(u0.y); r[2]=(short)f2bf(u0.z); r[3]=(short)f2bf(u0.w);
      r[4]=(short)f2bf(u1.x); r[5]=(short)f2bf(u1.y); r[6]=(short)f2bf(u1.z); r[7]=(short)f2bf(u1.w);
      wf[tI][kc] = r;
    }
  }

  float c_[4];
  {
    float4 cv = *(const float4*)(c0 + (size_t)bglob * H_ + kcell);
    c_[0] = cv.x; c_[1] = cv.y; c_[2] = cv.z; c_[3] = cv.w;
    const int b = tid >> 5, k = (tid & 31) * 4;
    float4 hv = *(const float4*)(h0 + (size_t)(bg * 16 + b) * H_ + k);
    uint2 hp = {bfpack2(hv.x, hv.y), bfpack2(hv.z, hv.w)};
    *(uint2*)&hs[0][b * 136 + k] = hp;
  }
  int cur = 0;
  __syncthreads();

#pragma unroll 1
  for (int ck = 0; ck < NCH; ck++) {
    const int t0 = ck * LCH;
    bool act = true;

    ushort4 pr[4];
    load_pr(pre2 + ((size_t)t0 * B_ + bglob) * G4_ + kq16, pr);

#pragma unroll 1
    for (int u = 0; u < LCH; u++) {
      const int t = t0 + u;
      const int dn = dns[t * 16 + l15];
      const bool nact = act && (dn == 0);
      if (__ballot(nact) == 0ULL) { act = false; break; }
      act = nact;

      ushort4 prn[4];
      const int un = (u + 1 < LCH) ? u + 1 : LCH - 1;
      load_pr(pre2 + ((size_t)(t0 + un) * B_ + bglob) * G4_ + kq16, prn);

      const unsigned short* hb = hs[cur];
      bf16x8 hf[4];
#pragma unroll
      for (int kc = 0; kc < 4; kc++)
        hf[kc] = *(const bf16x8*)&hb[l15 * 136 + kc * 32 + q * 8];

      f32x4 acc[4];
#pragma unroll
      for (int tI = 0; tI < 4; tI++) acc[tI] = (f32x4){0.f, 0.f, 0.f, 0.f};
#pragma unroll
      for (int tI = 0; tI < 4; tI++)
#pragma unroll
        for (int kc = 0; kc < 4; kc++)
          acc[tI] = __builtin_amdgcn_mfma_f32_16x16x32_bf16(
              wf[tI][kc], hf[kc], acc[tI], 0, 0, 0);

      float hv[4];
#pragma unroll
      for (int r = 0; r < 4; r++) {
        const float iv = acc[0][r] + bf2f(pr[r].x);
        const float fv = acc[1][r] + bf2f(pr[r].y);
        const float gv = acc[2][r] + bf2f(pr[r].z);
        const float ov = acc[3][r] + bf2f(pr[r].w);
        float cc = sigf(fv) * c_[r] + sigf(iv) * tanhf_(gv);
        c_[r] = cc;
        hv[r] = sigf(ov) * tanhf_(cc);
      }
      uint2 hp = {bfpack2(hv[0], hv[1]), bfpack2(hv[2], hv[3])};
      *(uint2*)&hs[cur ^ 1][l15 * 136 + kcell] = hp;
      if (act)
        *(uint2*)&hidden[((size_t)t * B_ + bglob) * H_ + kcell] = hp;
#pragma unroll
      for (int tI = 0; tI < 4; tI++) pr[tI] = prn[tI];
      barrier_lds();
      cur ^= 1;
    }

    if (!act) {
      ushort4 hv = *(const ushort4*)&hfin[((size_t)ck * B_ + bglob) * H_ + kcell];
      float4 cv = *(const float4*)&cfin[((size_t)ck * B_ + bglob) * H_ + kcell];
      c_[0] = cv.x; c_[1] = cv.y; c_[2] = cv.z; c_[3] = cv.w;
      *(ushort4*)&hs[cur][l15 * 136 + kcell] = hv;
    }
    barrier_lds();
  }
}

// ---------------------------------------------------------------------------
// K3: out[T*B][13] = hidden @ [W_pi; W_v]^T + [b_pi; b_v]   (unchanged)
// ---------------------------------------------------------------------------
__global__ __launch_bounds__(256) void k3_head(
    const unsigned short* __restrict__ hidden, const float* __restrict__ Wpi,
    const float* __restrict__ bpi, const float* __restrict__ Wv,
    const float* __restrict__ bv, float* __restrict__ out) {
  __shared__ unsigned short hs3[64 * 136];
  __shared__ float bias_s[16];

  const int tid = threadIdx.x;
  const int w = tid >> 6;
  const int lane = tid & 63;
  const int l15 = lane & 15;
  const int q = lane >> 4;
  const int m0 = blockIdx.x * 64;

  if (tid < 16) bias_s[tid] = (tid < 12) ? bpi[tid] : ((tid == 12) ? bv[0] : 0.f);

  bf16x8 wf3[4];
#pragma unroll
  for (int kc = 0; kc < 4; kc++) {
    float4 u0 = {0.f, 0.f, 0.f, 0.f}, u1 = {0.f, 0.f, 0.f, 0.f};
    if (l15 < 12) {
      const float* p = Wpi + (size_t)l15 * H_ + kc * 32 + q * 8;
      u0 = *(const float4*)p; u1 = *(const float4*)(p + 4);
    } else if (l15 == 12) {
      const float* p = Wv + kc * 32 + q * 8;
      u0 = *(const float4*)p; u1 = *(const float4*)(p + 4);
    }
    bf16x8 r;
    r[0]=(short)f2bf(u0.x); r[1]=(short)f2bf(u0.y); r[2]=(short)f2bf(u0.z); r[3]=(short)f2bf(u0.w);
    r[4]=(short)f2bf(u1.x); r[5]=(short)f2bf(u1.y); r[6]=(short)f2bf(u1.z); r[7]=(short)f2bf(u1.w);
    wf3[kc] = r;
  }

  {
    const int row = tid >> 2, ks = (tid & 3) * 32;
    const unsigned short* p = hidden + (size_t)(m0 + row) * H_ + ks;
#pragma unroll
    for (int i = 0; i < 4; i++)
      *(uint4*)&hs3[row * 136 + ks + i * 8] = *(const uint4*)(p + i * 8);
  }
  __syncthreads();

  f32x4 acc = (f32x4){0.f, 0.f, 0.f, 0.f};
#pragma unroll
  for (int kc = 0; kc < 4; kc++) {
    bf16x8 hf = *(bf16x8*)&hs3[(16 * w + l15) * 136 + kc * 32 + q * 8];
    acc = __builtin_amdgcn_mfma_f32_16x16x32_bf16(wf3[kc], hf, acc, 0, 0, 0);
  }

  const float4 bb = *(float4*)&bias_s[4 * q];
  const int m = m0 + 16 * w + l15;
  const size_t ro = (size_t)m * 13;
  float v0 = acc[0] + bb.x, v1 = acc[1] + bb.y, v2 = acc[2] + bb.z, v3 = acc[3] + bb.w;
  if (q < 3) {
    out[ro + 4 * q + 0] = v0;
    out[ro + 4 * q + 1] = v1;
    out[ro + 4 * q + 2] = v2;
    out[ro + 4 * q + 3] = v3;
  } else {
    out[ro + 12] = v0;
  }
}

// ---------------------------------------------------------------------------
// Workspace (ws, 167.8 MB):
//   pre2   bf16 [131072][512] @ 0            (cell-major-quad layout)
//   hidden bf16 [131072][128] @ 134,217,728
// Scratch in d_out (6.5 MB, overwritten by K3 at the end):
//   Wb2 bf16 [512][320] @ 0 (320 KB)   bias2 fp32 [512] @ 512 KB
//   hfin @ 1 MB, cfin @ 2 MB, needfix @ 4 MB
// ---------------------------------------------------------------------------
extern "C" void kernel_launch(void* const* d_in, const int* in_sizes, int n_in,
                              void* d_out, int out_size, void* d_ws, size_t ws_size,
                              hipStream_t stream) {
  const float* x    = (const float*)d_in[0];
  const int* done   = (const int*)d_in[1];
  const float* h0   = (const float*)d_in[2];
  const float* c0   = (const float*)d_in[3];
  const float* Wih  = (const float*)d_in[4];
  const float* Whh  = (const float*)d_in[5];
  const float* bih  = (const float*)d_in[6];
  const float* bhh  = (const float*)d_in[7];
  const float* Wpi  = (const float*)d_in[8];
  const float* bpi  = (const float*)d_in[9];
  const float* Wv   = (const float*)d_in[10];
  const float* bv   = (const float*)d_in[11];
  (void)in_sizes; (void)n_in; (void)out_size; (void)ws_size;

  unsigned short* pre2 = (unsigned short*)d_ws;
  unsigned short* hidden = pre2 + (size_t)TB_ * G4_;
  unsigned short* Wb   = (unsigned short*)d_out;
  float* bias2         = (float*)((char*)d_out + (512u << 10));
  unsigned short* hfin = (unsigned short*)((char*)d_out + (1u << 20));
  float* cfin          = (float*)((char*)d_out + (2u << 20));
  int* needfix         = (int*)((char*)d_out + (4u << 20));
  float* out = (float*)d_out;

  k0w_cvt<<<80, 256, 0, stream>>>(Wih, bih, bhh, Wb, bias2);
  k1_pregemm<<<TB_ / 128, 512, 0, stream>>>(x, Wb, bias2, pre2);
  k2a_chunk<<<256, 512, 0, stream>>>(pre2, Whh, done, hidden, hfin, cfin);
  k2b_par<<<256, 512, 0, stream>>>(pre2, Whh, h0, c0, done, hidden, hfin, cfin, needfix);
  k2c_guard<<<16, 512, 0, stream>>>(pre2, Whh, h0, c0, done, hidden, hfin, cfin, needfix);
  k3_head<<<TB_ / 64, 256, 0, stream>>>(hidden, Wpi, bpi, Wv, bv, out);
}